// Round 9
// baseline (1155.579 us; speedup 1.0000x reference)
//
#include <hip/hip_runtime.h>

typedef __bf16 bf16;
typedef __bf16 bf16x4 __attribute__((ext_vector_type(4)));
typedef __bf16 bf16x8 __attribute__((ext_vector_type(8)));
typedef float  f32x4  __attribute__((ext_vector_type(4)));

#define EMBED 1024
#define HEADS 16
#define HDIM  64
#define DFF   4096
#define BATCH 4
#define SEQ   2048
#define MROWS 8192   // BATCH*SEQ

// ---------------------------------------------------------------------------
// fp32 -> bf16 elementwise convert (n multiple of 8)
// ---------------------------------------------------------------------------
__global__ __launch_bounds__(256) void cvt_kernel(
    const float* __restrict__ x, bf16* __restrict__ y, int n)
{
  int i = (blockIdx.x * 256 + threadIdx.x) * 8;
  if (i >= n) return;
  float4 a = *(const float4*)(x + i);
  float4 b = *(const float4*)(x + i + 4);
  bf16x8 v;
  v[0] = (bf16)a.x; v[1] = (bf16)a.y; v[2] = (bf16)a.z; v[3] = (bf16)a.w;
  v[4] = (bf16)b.x; v[5] = (bf16)b.y; v[6] = (bf16)b.z; v[7] = (bf16)b.w;
  *(bf16x8*)(y + i) = v;
}

// ---------------------------------------------------------------------------
// Weight transpose-convert: W[K][N] fp32 -> Wt[N][K] bf16. 64x64 tile via LDS.
// ---------------------------------------------------------------------------
__global__ __launch_bounds__(256) void wt_kernel(
    const float* __restrict__ W, bf16* __restrict__ Wt, int K, int N)
{
  __shared__ __align__(16) float Ls[64 * 68];
  const int k0 = blockIdx.x * 64, n0 = blockIdx.y * 64;
  const int ty = threadIdx.x >> 4, tx = threadIdx.x & 15;
  #pragma unroll
  for (int r = 0; r < 4; ++r) {
    const int k = ty + r * 16;
    float4 v = *(const float4*)(W + (size_t)(k0 + k) * N + n0 + tx * 4);
    *(float4*)(Ls + k * 68 + tx * 4) = v;
  }
  __syncthreads();
  #pragma unroll
  for (int it = 0; it < 2; ++it) {
    const int c = it * 256 + threadIdx.x;
    const int n = c >> 3, kc = (c & 7) * 8;
    bf16x8 v;
    #pragma unroll
    for (int j = 0; j < 8; ++j) v[j] = (bf16)Ls[(kc + j) * 68 + n];
    *(bf16x8*)(Wt + (size_t)(n0 + n) * K + k0 + kc) = v;
  }
}

// ---------------------------------------------------------------------------
// bias concat: dst[0:n)=a, [n:2n)=b, [2n:3n)=c (c optional)
// ---------------------------------------------------------------------------
__global__ void cat3_kernel(float* __restrict__ dst, const float* __restrict__ a,
                            const float* __restrict__ b, const float* __restrict__ c, int n)
{
  int i = blockIdx.x * 256 + threadIdx.x;
  if (i < n) dst[i] = a[i];
  else if (i < 2 * n) dst[i] = b[i - n];
  else if (c && i < 3 * n) dst[i] = c[i - 2 * n];
}

// ---------------------------------------------------------------------------
// V transpose for attention: V[(b*Skv+key)*ldv + h*64 + d] ->
// Vt[((b*16+h)*64 + d)*Skv + key].  64key x 64d tile via LDS.
// ---------------------------------------------------------------------------
__global__ __launch_bounds__(256) void vtr_kernel(
    const bf16* __restrict__ V, int ldv, bf16* __restrict__ Vt, int Skv)
{
  __shared__ __align__(16) bf16 Ls[64 * 72];
  const int k0 = blockIdx.x * 64;
  const int bh = blockIdx.y, b = bh >> 4, h = bh & 15;
  const int t = threadIdx.x;
  {
    const int key = t >> 2, dc = (t & 3) * 16;
    const bf16* src = V + (size_t)(b * Skv + k0 + key) * ldv + h * HDIM + dc;
    bf16x8 a0 = *(const bf16x8*)src;
    bf16x8 a1 = *(const bf16x8*)(src + 8);
    *(bf16x8*)(Ls + key * 72 + dc) = a0;
    *(bf16x8*)(Ls + key * 72 + dc + 8) = a1;
  }
  __syncthreads();
  {
    const int d = t >> 2, kc = (t & 3) * 16;
    bf16x8 v0, v1;
    #pragma unroll
    for (int j = 0; j < 8; ++j) v0[j] = Ls[(kc + j) * 72 + d];
    #pragma unroll
    for (int j = 0; j < 8; ++j) v1[j] = Ls[(kc + 8 + j) * 72 + d];
    bf16* dst = Vt + ((size_t)(bh * HDIM + d)) * Skv + k0 + kc;
    *(bf16x8*)dst = v0;
    *(bf16x8*)(dst + 8) = v1;
  }
}

// ---------------------------------------------------------------------------
// async global->LDS, 16B per lane
// ---------------------------------------------------------------------------
__device__ __forceinline__ void gll16(const bf16* g, bf16* l) {
  __builtin_amdgcn_global_load_lds(
      (const __attribute__((address_space(1))) unsigned*)g,
      (__attribute__((address_space(3))) unsigned*)l, 16, 0, 0);
}

// ---------------------------------------------------------------------------
// 128x128-tile GEMM, 3-buffer counted-vmcnt pipeline (T4) + LDS XOR swizzle.
// Used for the N=1024 shapes (grid 512 keeps the chip full).
// ---------------------------------------------------------------------------
__global__ __launch_bounds__(256) void gemm128(
    const bf16* __restrict__ A, int lda, const bf16* __restrict__ Bt, int ldb,
    const float* __restrict__ bias, const bf16* __restrict__ res_b,
    const float* __restrict__ res_f, bf16* __restrict__ out_b,
    float* __restrict__ out_f, int N, int K, int relu)
{
  __shared__ __align__(16) bf16 As[3][128 * 32];
  __shared__ __align__(16) bf16 Bs[3][128 * 32];
  const int tid  = threadIdx.x;
  const int lane = tid & 63, wave = tid >> 6;
  const int quad = lane >> 4, l16 = lane & 15;
  const int wm = wave & 1, wn = wave >> 1;

  const int gx   = gridDim.x;
  const int nwg  = gx * gridDim.y;
  const int flat = blockIdx.y * gx + blockIdx.x;
  const int wg   = (flat & 7) * (nwg >> 3) + (flat >> 3);   // bijective: nwg%8==0
  const int m0 = (wg / gx) * 128, n0 = (wg % gx) * 128;

  const int c0row = tid >> 2;
  const int c0kc  = (((tid & 3) ^ ((tid >> 2) & 3) ^ ((tid >> 4) & 3))) * 8;
  const int c1row = 64 + c0row;

  const int co = ((quad ^ ((l16 & 3) ^ ((l16 >> 2) & 3)))) * 8;

  const bf16* a0 = A  + (size_t)(m0 + c0row) * lda + c0kc;
  const bf16* b0 = Bt + (size_t)(n0 + c0row) * ldb + c0kc;
  const bf16* a1 = A  + (size_t)(m0 + c1row) * lda + c0kc;
  const bf16* b1 = Bt + (size_t)(n0 + c1row) * ldb + c0kc;

  f32x4 acc[4][4];
  #pragma unroll
  for (int i = 0; i < 4; ++i)
    #pragma unroll
    for (int j = 0; j < 4; ++j) acc[i][j] = f32x4{0, 0, 0, 0};

  auto stage = [&](int k0, int buf) {
    gll16(a0 + k0, As[buf] + wave * 512);
    gll16(b0 + k0, Bs[buf] + wave * 512);
    gll16(a1 + k0, As[buf] + 2048 + wave * 512);
    gll16(b1 + k0, Bs[buf] + 2048 + wave * 512);
  };

  const int nk = K >> 5;
  stage(0, 0);
  if (nk > 1) stage(32, 1);

  int cur = 0;
  for (int t = 0; t < nk; ++t) {
    if (t + 1 < nk) asm volatile("s_waitcnt vmcnt(4)" ::: "memory");
    else            asm volatile("s_waitcnt vmcnt(0)" ::: "memory");
    __builtin_amdgcn_s_barrier();
    __builtin_amdgcn_sched_barrier(0);

    bf16x8 af[4], bfr[4];
    #pragma unroll
    for (int i = 0; i < 4; ++i)
      af[i] = *(const bf16x8*)(As[cur] + (wm * 64 + i * 16 + l16) * 32 + co);
    #pragma unroll
    for (int j = 0; j < 4; ++j)
      bfr[j] = *(const bf16x8*)(Bs[cur] + (wn * 64 + j * 16 + l16) * 32 + co);
    #pragma unroll
    for (int i = 0; i < 4; ++i)
      #pragma unroll
      for (int j = 0; j < 4; ++j)
        acc[i][j] = __builtin_amdgcn_mfma_f32_16x16x32_bf16(af[i], bfr[j], acc[i][j], 0, 0, 0);

    if (t + 2 < nk) {
      int nb = cur + 2; if (nb >= 3) nb -= 3;
      stage((t + 2) << 5, nb);
    }
    cur = (cur + 1 == 3) ? 0 : cur + 1;
  }

  #pragma unroll
  for (int j = 0; j < 4; ++j) {
    const int col = n0 + wn * 64 + j * 16 + l16;
    const float bv = bias ? bias[col] : 0.f;
    #pragma unroll
    for (int i = 0; i < 4; ++i) {
      #pragma unroll
      for (int r = 0; r < 4; ++r) {
        const int row = m0 + wm * 64 + i * 16 + quad * 4 + r;
        const size_t idx = (size_t)row * N + col;
        float v = acc[i][j][r] + bv;
        if (res_b) v += (float)res_b[idx];
        if (res_f) v += res_f[idx];
        if (relu)  v = fmaxf(v, 0.f);
        if (out_b) out_b[idx] = (bf16)v;
        if (out_f) out_f[idx] = v;
      }
    }
  }
}

// ---------------------------------------------------------------------------
// 256x256-tile GEMM v2 — counted-vmcnt double-buffer (T3-min + T4):
// 512 thr = 8 waves (2M x 4N), per-wave C = 128x64 (acc[8][4]); BK=64;
// LDS = 2 x (A 32KB + B 32KB) = 128 KiB, 1 block/CU.
// Per K-tile t: (a) issue 8 gll for tile t+1 into buf^1; (b) vmcnt(8) —
// tile t's 8 older loads landed, t+1's stay IN FLIGHT across the barrier
// (never drains in main loop — fixes the round-3 failure); (c) raw
// s_barrier + sched_barrier; (d) 4 quadrant-phases x 16 MFMA with setprio,
// frags via swizzled ds_read_b128; (e) raw s_barrier (all reads of buf[t&1]
// done before any wave's t+2 gll can overwrite it).
// Race audit: writes to buf b are issued only after the end-barrier of the
// iteration that last read b; reads of b happen only after all waves'
// vmcnt+barrier.  Swizzle = fattn's verified pattern (linear DMA dest +
// inverse-XOR source + XOR read; 8 lanes/bank-group = b128 floor).
// XCD-bijective blockIdx swizzle (T1); nwg%8==0 for all uses.
// ---------------------------------------------------------------------------
__global__ __launch_bounds__(512, 2) void gemm256(
    const bf16* __restrict__ A, int lda, const bf16* __restrict__ Bt, int ldb,
    const float* __restrict__ bias, const bf16* __restrict__ res_b,
    const float* __restrict__ res_f, bf16* __restrict__ out_b,
    float* __restrict__ out_f, int N, int K, int relu)
{
  __shared__ __align__(16) bf16 As[2][256 * 64];
  __shared__ __align__(16) bf16 Bs[2][256 * 64];
  const int tid  = threadIdx.x;
  const int lane = tid & 63, wave = tid >> 6;
  const int quad = lane >> 4, l16 = lane & 15;
  const int wm = wave & 1, wn = wave >> 1;      // 2 x 4 wave grid

  const int gx   = gridDim.x;
  const int nwg  = gx * (int)gridDim.y;
  const int flat = blockIdx.y * gx + blockIdx.x;
  const int wg   = (flat & 7) * (nwg >> 3) + (flat >> 3);   // bijective: nwg%8==0
  const int m0 = (wg / gx) * 256, n0 = (wg % gx) * 256;

  // staging: lane covers row (tid>>3) of each 64-row group, block tid&7;
  // source elem offset inverse-swizzled (row&7 == (tid>>3)&7)
  const int srow = tid >> 3;
  const int se   = ((tid & 7) ^ ((tid >> 3) & 7)) << 3;

  // swizzled read offsets (row&7 == l16&7 for rows ≡ l16 mod 16)
  const int sw  = l16 & 7;
  const int co0 = (quad ^ sw) << 3;             // k-slot 0: elems quad*8..
  const int co1 = ((4 + quad) ^ sw) << 3;       // k-slot 1: elems 32+quad*8..

  const bf16* aA = A  + (size_t)(m0 + srow) * lda + se;
  const bf16* aB = Bt + (size_t)(n0 + srow) * ldb + se;
  const size_t a64 = (size_t)64 * lda, b64 = (size_t)64 * ldb;

  f32x4 acc[8][4];
  #pragma unroll
  for (int i = 0; i < 8; ++i)
    #pragma unroll
    for (int j = 0; j < 4; ++j) acc[i][j] = f32x4{0, 0, 0, 0};

  auto stage = [&](int t, int buf) {
    const int k0 = t << 6;
    #pragma unroll
    for (int g = 0; g < 4; ++g) {
      gll16(aA + (size_t)g * a64 + k0, As[buf] + (g * 64 + wave * 8) * 64);
      gll16(aB + (size_t)g * b64 + k0, Bs[buf] + (g * 64 + wave * 8) * 64);
    }
  };

  const int nt = K >> 6;
  stage(0, 0);

  for (int t = 0; t < nt; ++t) {
    const int cur = t & 1;
    if (t + 1 < nt) {
      stage(t + 1, cur ^ 1);                    // issue BEFORE the wait
      asm volatile("s_waitcnt vmcnt(8)" ::: "memory");   // tile t landed
    } else {
      asm volatile("s_waitcnt vmcnt(0)" ::: "memory");   // tail drain
    }
    __builtin_amdgcn_s_barrier();
    __builtin_amdgcn_sched_barrier(0);

    const bf16* Ac = As[cur];
    const bf16* Bc = Bs[cur];
    #pragma unroll
    for (int ph = 0; ph < 4; ++ph) {
      const int ih = ph >> 1, jh = ph & 1;      // C-quadrant
      bf16x8 af[4][2], bfr[2][2];
      #pragma unroll
      for (int ii = 0; ii < 4; ++ii) {
        const int row = wm * 128 + (ih * 4 + ii) * 16 + l16;
        af[ii][0] = *(const bf16x8*)(Ac + row * 64 + co0);
        af[ii][1] = *(const bf16x8*)(Ac + row * 64 + co1);
      }
      #pragma unroll
      for (int jj = 0; jj < 2; ++jj) {
        const int row = wn * 64 + (jh * 2 + jj) * 16 + l16;
        bfr[jj][0] = *(const bf16x8*)(Bc + row * 64 + co0);
        bfr[jj][1] = *(const bf16x8*)(Bc + row * 64 + co1);
      }
      __builtin_amdgcn_s_setprio(1);
      #pragma unroll
      for (int ii = 0; ii < 4; ++ii)
        #pragma unroll
        for (int jj = 0; jj < 2; ++jj) {
          acc[ih * 4 + ii][jh * 2 + jj] = __builtin_amdgcn_mfma_f32_16x16x32_bf16(
              af[ii][0], bfr[jj][0], acc[ih * 4 + ii][jh * 2 + jj], 0, 0, 0);
          acc[ih * 4 + ii][jh * 2 + jj] = __builtin_amdgcn_mfma_f32_16x16x32_bf16(
              af[ii][1], bfr[jj][1], acc[ih * 4 + ii][jh * 2 + jj], 0, 0, 0);
        }
      __builtin_amdgcn_s_setprio(0);
    }
    __builtin_amdgcn_s_barrier();   // reads of buf[cur] done; safe to overwrite next iter
  }

  #pragma unroll
  for (int j = 0; j < 4; ++j) {
    const int col = n0 + wn * 64 + j * 16 + l16;
    const float bv = bias ? bias[col] : 0.f;
    #pragma unroll
    for (int i = 0; i < 8; ++i) {
      #pragma unroll
      for (int r = 0; r < 4; ++r) {
        const int row = m0 + wm * 128 + i * 16 + quad * 4 + r;
        const size_t idx = (size_t)row * N + col;
        float v = acc[i][j][r] + bv;
        if (res_b) v += (float)res_b[idx];
        if (res_f) v += res_f[idx];
        if (relu)  v = fmaxf(v, 0.f);
        if (out_b) out_b[idx] = (bf16)v;
        if (out_f) out_f[idx] = v;
      }
    }
  }
}

// ---------------------------------------------------------------------------
// LayerNorm over last dim (1024): fp32 in, fp32 params, bf16 and/or fp32 out.
// ---------------------------------------------------------------------------
__global__ __launch_bounds__(256) void ln_kernel(
    const float* __restrict__ x, const float* __restrict__ g, const float* __restrict__ b,
    bf16* __restrict__ out_b, float* __restrict__ out_f)
{
  __shared__ float red[8];
  const int tid = threadIdx.x, lane = tid & 63, wave = tid >> 6;
  const float* xr = x + (size_t)blockIdx.x * EMBED;
  float4 v = *(const float4*)(xr + tid * 4);
  float vv[4] = {v.x, v.y, v.z, v.w};
  float s  = vv[0] + vv[1] + vv[2] + vv[3];
  float s2 = vv[0]*vv[0] + vv[1]*vv[1] + vv[2]*vv[2] + vv[3]*vv[3];
  #pragma unroll
  for (int off = 32; off >= 1; off >>= 1) {
    s  += __shfl_xor(s, off);
    s2 += __shfl_xor(s2, off);
  }
  if (lane == 0) { red[wave] = s; red[4 + wave] = s2; }
  __syncthreads();
  s  = red[0] + red[1] + red[2] + red[3];
  s2 = red[4] + red[5] + red[6] + red[7];
  const float mu  = s * (1.f / EMBED);
  const float var = s2 * (1.f / EMBED) - mu * mu;
  const float rs  = rsqrtf(fmaxf(var, 0.f) + 1e-5f);
  #pragma unroll
  for (int i = 0; i < 4; ++i) {
    const int col = tid * 4 + i;
    const float o = (vv[i] - mu) * rs * g[col] + b[col];
    const size_t idx = (size_t)blockIdx.x * EMBED + col;
    if (out_b) out_b[idx] = (bf16)o;
    if (out_f) out_f[idx] = o;
  }
}

// ---------------------------------------------------------------------------
// MFMA flash attention (round-6 verified form).  Swapped QK^T (mfma(K,Q))
// => lane-local softmax.  K/V staged via global_load_lds (linear dest +
// swizzled source/read), double-buffered, prefetch-before-compute, one
// barrier per K-tile.  Raw-domain max, 1/sqrt(d) folded into exp via fma.
// Causal grid pairs q-tiles bx and 15-bx (load balance).
// ---------------------------------------------------------------------------
__global__ __launch_bounds__(256) void fattn_kernel(
    const bf16* __restrict__ Q, int ldq, const bf16* __restrict__ K, int ldk,
    const bf16* __restrict__ Vt, bf16* __restrict__ Y, int Skv, int causal)
{
  constexpr int PLD = 72;                       // P-buffer stride (conflict-free)
  __shared__ __align__(16) bf16 Ks[2][64 * 64]; // [key][d], swizzled
  __shared__ __align__(16) bf16 Vs[2][64 * 64]; // [d][key], swizzled
  __shared__ __align__(16) bf16 Ps[4 * 32 * PLD];

  const int tid  = threadIdx.x;
  const int lane = tid & 63, wave = tid >> 6;
  const int quad = lane >> 4, l16 = lane & 15;
  const int bh = blockIdx.y, b = bh >> 4, h = bh & 15;

  const bf16* Kb = K + (size_t)b * Skv * ldk + h * HDIM;
  const bf16* Vb = Vt + (size_t)(bh * HDIM) * Skv;

  const int sr = lane >> 3;
  const int se = ((lane & 7) ^ sr) << 3;        // swizzled source elem offset

  const int sw  = l16 & 7;
  const int co0 = (quad ^ sw) << 3;
  const int co1 = ((4 + quad) ^ sw) << 3;

  auto stage = [&](int kt, int buf) {
    const int k0 = kt * 64;
    const int r0 = wave * 16;
    gll16(Kb + (size_t)(k0 + r0 + sr) * ldk + se,     &Ks[buf][(r0)     * 64]);
    gll16(Kb + (size_t)(k0 + r0 + 8 + sr) * ldk + se, &Ks[buf][(r0 + 8) * 64]);
    gll16(Vb + (size_t)(r0 + sr) * Skv + k0 + se,     &Vs[buf][(r0)     * 64]);
    gll16(Vb + (size_t)(r0 + 8 + sr) * Skv + k0 + se, &Vs[buf][(r0 + 8) * 64]);
  };

  bf16* Pw = Ps + wave * 32 * PLD;
  const int npass = causal ? 2 : 1;

  for (int pass = 0; pass < npass; ++pass) {
    const int qt = causal ? (pass == 0 ? (int)blockIdx.x
                                       : (SEQ / 128 - 1 - (int)blockIdx.x))
                          : (int)blockIdx.x;
    const int q0  = qt * 128;
    const int wq0 = q0 + wave * 32;

    bf16x8 qf[2][2];
    #pragma unroll
    for (int i = 0; i < 2; ++i) {
      const bf16* qp = Q + (size_t)(b * SEQ + wq0 + i * 16 + l16) * ldq + h * HDIM;
      qf[i][0] = *(const bf16x8*)(qp + quad * 8);
      qf[i][1] = *(const bf16x8*)(qp + 32 + quad * 8);
    }

    f32x4 O[2][4];
    float m_run[2], l_run[2];
    #pragma unroll
    for (int i = 0; i < 2; ++i)
      #pragma unroll
      for (int nt = 0; nt < 4; ++nt) O[i][nt] = f32x4{0, 0, 0, 0};
    #pragma unroll
    for (int i = 0; i < 2; ++i) { m_run[i] = -1e30f; l_run[i] = 0.f; }

    const int nkt = causal ? (q0 / 64 + 2) : (Skv / 64);

    stage(0, 0);
    __syncthreads();

    for (int kt = 0; kt < nkt; ++kt) {
      const int cur = kt & 1;
      const int k0 = kt * 64;
      if (kt + 1 < nkt) stage(kt + 1, cur ^ 1);

      const bf16* Kc = Ks[cur];
      const bf16* Vc = Vs[cur];

      // ---- S^T = K Q^T  (col=l16 -> q, row=quad*4+r -> key), raw (unscaled)
      f32x4 s[2][4];
      __builtin_amdgcn_s_setprio(1);
      #pragma unroll
      for (int nt = 0; nt < 4; ++nt) {
        const int row = nt * 16 + l16;
        bf16x8 kf0 = *(const bf16x8*)(Kc + row * 64 + co0);
        bf16x8 kf1 = *(const bf16x8*)(Kc + row * 64 + co1);
        #pragma unroll
        for (int i = 0; i < 2; ++i) {
          f32x4 t = f32x4{0, 0, 0, 0};
          t = __builtin_amdgcn_mfma_f32_16x16x32_bf16(kf0, qf[i][0], t, 0, 0, 0);
          t = __builtin_amdgcn_mfma_f32_16x16x32_bf16(kf1, qf[i][1], t, 0, 0, 0);
          s[i][nt] = t;
        }
      }
      __builtin_amdgcn_s_setprio(0);

      if (causal && (k0 + 63 > wq0)) {          // mask only on diagonal tiles
        #pragma unroll
        for (int i = 0; i < 2; ++i) {
          const int q = wq0 + i * 16 + l16;
          #pragma unroll
          for (int nt = 0; nt < 4; ++nt) {
            #pragma unroll
            for (int r = 0; r < 4; ++r) {
              const int key = k0 + nt * 16 + quad * 4 + r;
              if (key > q) s[i][nt][r] = -1e30f;
            }
          }
        }
      }

      // ---- online softmax: raw-domain max, scale folded into exp via fma
      #pragma unroll
      for (int i = 0; i < 2; ++i) {
        float pm = s[i][0][0];
        #pragma unroll
        for (int nt = 0; nt < 4; ++nt)
          #pragma unroll
          for (int r = 0; r < 4; ++r) pm = fmaxf(pm, s[i][nt][r]);
        pm = fmaxf(pm, __shfl_xor(pm, 16));
        pm = fmaxf(pm, __shfl_xor(pm, 32));
        const float m_new = fmaxf(m_run[i], pm);
        const float al = __expf((m_run[i] - m_new) * 0.125f);
        m_run[i] = m_new;
        const float mc = m_new * 0.125f;
        float ls = 0.f;
        #pragma unroll
        for (int nt = 0; nt < 4; ++nt) {
          #pragma unroll
          for (int r = 0; r < 4; ++r) {
            const float e = __expf(fmaf(s[i][nt][r], 0.125f, -mc));
            s[i][nt][r] = e;
            ls += e;
          }
        }
        ls += __shfl_xor(ls, 16);
        ls += __shfl_xor(ls, 32);
        l_run[i] = l_run[i] * al + ls;
        // P store: row q=i*16+l16, keys nt*16+quad*4..+3 contiguous -> b64
        #pragma unroll
        for (int nt = 0; nt < 4; ++nt) {
          bf16x4 pk;
          pk[0] = (bf16)s[i][nt][0]; pk[1] = (bf16)s[i][nt][1];
          pk[2] = (bf16)s[i][nt][2]; pk[3] = (bf16)s[i][nt][3];
          *(bf16x4*)(Pw + (i * 16 + l16) * PLD + nt * 16 + quad * 4) = pk;
        }
        // O rescale: O rows are quad*4+r -> pull al from lane (quad*4+r)
        float alo[4];
        #pragma unroll
        for (int r = 0; r < 4; ++r) alo[r] = __shfl(al, quad * 4 + r);
        #pragma unroll
        for (int nt = 0; nt < 4; ++nt)
          #pragma unroll
          for (int r = 0; r < 4; ++r) O[i][nt][r] *= alo[r];
      }

      // ---- O += P V ----
      bf16x8 pf[2][2];
      #pragma unroll
      for (int i = 0; i < 2; ++i) {
        pf[i][0] = *(const bf16x8*)(Pw + (i * 16 + l16) * PLD + quad * 8);
        pf[i][1] = *(const bf16x8*)(Pw + (i * 16 + l16) * PLD + 32 + quad * 8);
      }
      __builtin_amdgcn_s_setprio(1);
      #pragma unroll
      for (int nt = 0; nt < 4; ++nt) {
        const int row = nt * 16 + l16;
        bf16x8 vf0 = *(const bf16x8*)(Vc + row * 64 + co0);
        bf16x8 vf1 = *(const bf16x8*)(Vc + row * 64 + co1);
        #pragma unroll
        for (int i = 0; i < 2; ++i) {
          O[i][nt] = __builtin_amdgcn_mfma_f32_16x16x32_bf16(pf[i][0], vf0, O[i][nt], 0, 0, 0);
          O[i][nt] = __builtin_amdgcn_mfma_f32_16x16x32_bf16(pf[i][1], vf1, O[i][nt], 0, 0, 0);
        }
      }
      __builtin_amdgcn_s_setprio(0);
      __syncthreads();
    }

    #pragma unroll
    for (int i = 0; i < 2; ++i) {
      float inv[4];
      #pragma unroll
      for (int r = 0; r < 4; ++r) {
        const float lv = __shfl(l_run[i], quad * 4 + r);
        inv[r] = 1.f / lv;
      }
      #pragma unroll
      for (int nt = 0; nt < 4; ++nt) {
        #pragma unroll
        for (int r = 0; r < 4; ++r) {
          const int q = wq0 + i * 16 + quad * 4 + r;
          Y[((size_t)(b * SEQ + q)) * EMBED + h * HDIM + nt * 16 + l16] = (bf16)(O[i][nt][r] * inv[r]);
        }
      }
    }
  }
}

__global__ void fill_kernel(float* out, float v, int n) {
  int i = blockIdx.x * 256 + threadIdx.x;
  if (i < n) out[i] = v;
}

// ---------------------------------------------------------------------------
extern "C" void kernel_launch(void* const* d_in, const int* in_sizes, int n_in,
                              void* d_out, int out_size, void* d_ws, size_t ws_size,
                              hipStream_t stream)
{
  const float* tgt    = (const float*)d_in[0];
  const float* mem    = (const float*)d_in[1];
  const float* sa_Wq  = (const float*)d_in[3];
  const float* sa_Wqb = (const float*)d_in[4];
  const float* sa_Wk  = (const float*)d_in[5];
  const float* sa_Wkb = (const float*)d_in[6];
  const float* sa_Wv  = (const float*)d_in[7];
  const float* sa_Wvb = (const float*)d_in[8];
  const float* sa_A   = (const float*)d_in[9];
  const float* sa_Ab  = (const float*)d_in[10];
  const float* ca_Wq  = (const float*)d_in[11];
  const float* ca_Wqb = (const float*)d_in[12];
  const float* ca_Wk  = (const float*)d_in[13];
  const float* ca_Wkb = (const float*)d_in[14];
  const float* ca_Wv  = (const float*)d_in[15];
  const float* ca_Wvb = (const float*)d_in[16];
  const float* ca_A   = (const float*)d_in[17];
  const float* ca_Ab  = (const float*)d_in[18];
  const float* l1W    = (const float*)d_in[19];
  const float* l1b    = (const float*)d_in[20];
  const float* l2W    = (const float*)d_in[21];
  const float* l2b    = (const float*)d_in[22];
  const float* g1     = (const float*)d_in[23];
  const float* b1     = (const float*)d_in[24];
  const float* g2     = (const float*)d_in[25];
  const float* b2     = (const float*)d_in[26];
  const float* g3     = (const float*)d_in[27];
  const float* b3     = (const float*)d_in[28];

  const size_t MB = 1024 * 1024;
  const size_t NEED = 80 * MB + 4096;
  if (ws_size < NEED) {
    fill_kernel<<<(out_size + 255) / 256, 256, 0, stream>>>((float*)d_out, 3.0f, out_size);
    return;
  }

  char* ws = (char*)d_ws;
  const size_t MD = (size_t)MROWS * EMBED;       // 8M elements
  // phase A
  bf16*  qkv   = (bf16*)ws;                      // [8192][3072] 48 MB
  bf16*  yb    = (bf16*)(ws + 48 * MB);          // 16 MB attention output
  bf16*  wqkvt = (bf16*)(ws + 48 * MB);          // 6 MB weights (dead before fattn writes yb)
  float* qkvbias = (float*)(ws + 54 * MB + 512 * 1024);
  // phase B
  bf16*  kvb   = (bf16*)ws;                      // [8192][2048] 32 MB
  bf16*  qB    = (bf16*)(ws + 32 * MB);          // 16 MB
  bf16*  wkvt  = (bf16*)(ws + 48 * MB);          // 4 MB
  bf16*  wqt   = (bf16*)(ws + 52 * MB);          // 2 MB
  float* kvbias = (float*)(ws + 54 * MB + 512 * 1024);
  // shared
  bf16*  awt   = (bf16*)ws;                      // 2 MB out-proj Wt (qkv/kvb dead)
  bf16*  xb    = (bf16*)(ws + 64 * MB);          // 16 MB LN output stream
  // phase C
  bf16*  hb    = (bf16*)ws;                      // [8192][2048] 32 MB hidden half
  bf16*  l1t   = (bf16*)(ws + 32 * MB);          // 8 MB
  bf16*  l2t   = (bf16*)(ws + 40 * MB);          // 8 MB
  // d_out regions
  float* P   = (float*)d_out;                    // fp32 pre-LN scratch (32 MB)
  bf16*  inb = (bf16*)d_out;                     // converted tgt/mem (16 MB)
  bf16*  vtg = (bf16*)((char*)d_out + 16 * MB);  // V^T for attention (16 MB)

  dim3 blk(256);
  dim3 blk512(512);
  dim3 gQKV(3072 / 256, MROWS / 256);   // (12,32) gemm256, 384 wg
  dim3 gKV(2048 / 256, MROWS / 256);    // (8,32)  gemm256, 256 wg
  dim3 gF1(2048 / 256, MROWS / 256);    // (8,32)  gemm256, 256 wg
  dim3 gEE(EMBED / 128, MROWS / 128);   // (8,64)  gemm128, 512 wg
  dim3 gATC(SEQ / 256, BATCH * HEADS);  // (8,64)  causal: paired q-tiles
  dim3 gAT(SEQ / 128, BATCH * HEADS);   // (16,64) cross
  dim3 gVT(SEQ / 64, BATCH * HEADS);    // (32,64)
  dim3 gWee(16, 16);
  const int ncv = (int)(MD / 8 / 256);

  // ---- Phase A: self-attention ----
  cvt_kernel<<<ncv, blk, 0, stream>>>(tgt, inb, (int)MD);
  wt_kernel<<<gWee, blk, 0, stream>>>(sa_Wq, wqkvt, EMBED, EMBED);
  wt_kernel<<<gWee, blk, 0, stream>>>(sa_Wk, wqkvt + 1024 * 1024, EMBED, EMBED);
  wt_kernel<<<gWee, blk, 0, stream>>>(sa_Wv, wqkvt + 2 * 1024 * 1024, EMBED, EMBED);
  cat3_kernel<<<12, blk, 0, stream>>>(qkvbias, sa_Wqb, sa_Wkb, sa_Wvb, EMBED);
  gemm256<<<gQKV, blk512, 0, stream>>>(inb, EMBED, wqkvt, EMBED, qkvbias, nullptr, nullptr, qkv, nullptr, 3072, EMBED, 0);
  vtr_kernel<<<gVT, blk, 0, stream>>>(qkv + 2048, 3072, vtg, SEQ);
  fattn_kernel<<<gATC, blk, 0, stream>>>(qkv, 3072, qkv + 1024, 3072, vtg, yb, SEQ, 1);
  wt_kernel<<<gWee, blk, 0, stream>>>(sa_A, awt, EMBED, EMBED);
  gemm128<<<gEE, blk, 0, stream>>>(yb, EMBED, awt, EMBED, sa_Ab, nullptr, tgt, nullptr, P, EMBED, EMBED, 0);
  ln_kernel<<<MROWS, blk, 0, stream>>>(P, g1, b1, xb, nullptr);

  // ---- Phase B: cross-attention ----
  cvt_kernel<<<ncv, blk, 0, stream>>>(mem, inb, (int)MD);
  wt_kernel<<<gWee, blk, 0, stream>>>(ca_Wk, wkvt, EMBED, EMBED);
  wt_kernel<<<gWee, blk, 0, stream>>>(ca_Wv, wkvt + 1024 * 1024, EMBED, EMBED);
  wt_kernel<<<gWee, blk, 0, stream>>>(ca_Wq, wqt, EMBED, EMBED);
  cat3_kernel<<<8, blk, 0, stream>>>(kvbias, ca_Wkb, ca_Wvb, nullptr, EMBED);
  gemm256<<<gKV, blk512, 0, stream>>>(inb, EMBED, wkvt, EMBED, kvbias, nullptr, nullptr, kvb, nullptr, 2048, EMBED, 0);
  gemm128<<<gEE, blk, 0, stream>>>(xb, EMBED, wqt, EMBED, ca_Wqb, nullptr, nullptr, qB, nullptr, EMBED, EMBED, 0);
  vtr_kernel<<<gVT, blk, 0, stream>>>(kvb + 1024, 2048, vtg, SEQ);
  fattn_kernel<<<gAT, blk, 0, stream>>>(qB, 1024, kvb, 2048, vtg, yb, SEQ, 0);
  wt_kernel<<<gWee, blk, 0, stream>>>(ca_A, awt, EMBED, EMBED);
  gemm128<<<gEE, blk, 0, stream>>>(yb, EMBED, awt, EMBED, ca_Ab, xb, nullptr, nullptr, P, EMBED, EMBED, 0);
  ln_kernel<<<MROWS, blk, 0, stream>>>(P, g2, b2, xb, nullptr);

  // ---- Phase C: FFN (split-K over DFF halves) ----
  wt_kernel<<<dim3(16, 64), blk, 0, stream>>>(l1W, l1t, EMBED, DFF);
  wt_kernel<<<dim3(64, 16), blk, 0, stream>>>(l2W, l2t, DFF, EMBED);
  gemm256<<<gF1, blk512, 0, stream>>>(xb, EMBED, l1t, EMBED, l1b, nullptr, nullptr, hb, nullptr, 2048, EMBED, 1);
  gemm128<<<gEE, blk, 0, stream>>>(hb, 2048, l2t, DFF, l2b, xb, nullptr, nullptr, P, EMBED, 2048, 0);
  gemm256<<<gF1, blk512, 0, stream>>>(xb, EMBED, l1t + (size_t)2048 * 1024, EMBED, l1b + 2048, nullptr, nullptr, hb, nullptr, 2048, EMBED, 1);
  gemm128<<<gEE, blk, 0, stream>>>(hb, 2048, l2t + 2048, DFF, nullptr, nullptr, P, nullptr, P, EMBED, 2048, 0);
  ln_kernel<<<MROWS, blk, 0, stream>>>(P, g3, b3, nullptr, (float*)d_out);
}

// Round 10
// 1109.162 us; speedup vs baseline: 1.0418x; 1.0418x over previous
//
#include <hip/hip_runtime.h>

typedef __bf16 bf16;
typedef __bf16 bf16x4 __attribute__((ext_vector_type(4)));
typedef __bf16 bf16x8 __attribute__((ext_vector_type(8)));
typedef float  f32x4  __attribute__((ext_vector_type(4)));

#define EMBED 1024
#define HEADS 16
#define HDIM  64
#define DFF   4096
#define BATCH 4
#define SEQ   2048
#define MROWS 8192   // BATCH*SEQ

// ---------------------------------------------------------------------------
// fp32 -> bf16 elementwise convert (n multiple of 8)
// ---------------------------------------------------------------------------
__global__ __launch_bounds__(256) void cvt_kernel(
    const float* __restrict__ x, bf16* __restrict__ y, int n)
{
  int i = (blockIdx.x * 256 + threadIdx.x) * 8;
  if (i >= n) return;
  float4 a = *(const float4*)(x + i);
  float4 b = *(const float4*)(x + i + 4);
  bf16x8 v;
  v[0] = (bf16)a.x; v[1] = (bf16)a.y; v[2] = (bf16)a.z; v[3] = (bf16)a.w;
  v[4] = (bf16)b.x; v[5] = (bf16)b.y; v[6] = (bf16)b.z; v[7] = (bf16)b.w;
  *(bf16x8*)(y + i) = v;
}

// ---------------------------------------------------------------------------
// Weight transpose-convert: W[K][N] fp32 -> Wt[N][K] bf16. 64x64 tile via LDS.
// ---------------------------------------------------------------------------
__global__ __launch_bounds__(256) void wt_kernel(
    const float* __restrict__ W, bf16* __restrict__ Wt, int K, int N)
{
  __shared__ __align__(16) float Ls[64 * 68];
  const int k0 = blockIdx.x * 64, n0 = blockIdx.y * 64;
  const int ty = threadIdx.x >> 4, tx = threadIdx.x & 15;
  #pragma unroll
  for (int r = 0; r < 4; ++r) {
    const int k = ty + r * 16;
    float4 v = *(const float4*)(W + (size_t)(k0 + k) * N + n0 + tx * 4);
    *(float4*)(Ls + k * 68 + tx * 4) = v;
  }
  __syncthreads();
  #pragma unroll
  for (int it = 0; it < 2; ++it) {
    const int c = it * 256 + threadIdx.x;
    const int n = c >> 3, kc = (c & 7) * 8;
    bf16x8 v;
    #pragma unroll
    for (int j = 0; j < 8; ++j) v[j] = (bf16)Ls[(kc + j) * 68 + n];
    *(bf16x8*)(Wt + (size_t)(n0 + n) * K + k0 + kc) = v;
  }
}

// ---------------------------------------------------------------------------
// bias concat: dst[0:n)=a, [n:2n)=b, [2n:3n)=c (c optional)
// ---------------------------------------------------------------------------
__global__ void cat3_kernel(float* __restrict__ dst, const float* __restrict__ a,
                            const float* __restrict__ b, const float* __restrict__ c, int n)
{
  int i = blockIdx.x * 256 + threadIdx.x;
  if (i < n) dst[i] = a[i];
  else if (i < 2 * n) dst[i] = b[i - n];
  else if (c && i < 3 * n) dst[i] = c[i - 2 * n];
}

// ---------------------------------------------------------------------------
// V transpose for attention: V[(b*Skv+key)*ldv + h*64 + d] ->
// Vt[((b*16+h)*64 + d)*Skv + key].  64key x 64d tile via LDS.
// ---------------------------------------------------------------------------
__global__ __launch_bounds__(256) void vtr_kernel(
    const bf16* __restrict__ V, int ldv, bf16* __restrict__ Vt, int Skv)
{
  __shared__ __align__(16) bf16 Ls[64 * 72];
  const int k0 = blockIdx.x * 64;
  const int bh = blockIdx.y, b = bh >> 4, h = bh & 15;
  const int t = threadIdx.x;
  {
    const int key = t >> 2, dc = (t & 3) * 16;
    const bf16* src = V + (size_t)(b * Skv + k0 + key) * ldv + h * HDIM + dc;
    bf16x8 a0 = *(const bf16x8*)src;
    bf16x8 a1 = *(const bf16x8*)(src + 8);
    *(bf16x8*)(Ls + key * 72 + dc) = a0;
    *(bf16x8*)(Ls + key * 72 + dc + 8) = a1;
  }
  __syncthreads();
  {
    const int d = t >> 2, kc = (t & 3) * 16;
    bf16x8 v0, v1;
    #pragma unroll
    for (int j = 0; j < 8; ++j) v0[j] = Ls[(kc + j) * 72 + d];
    #pragma unroll
    for (int j = 0; j < 8; ++j) v1[j] = Ls[(kc + 8 + j) * 72 + d];
    bf16* dst = Vt + ((size_t)(bh * HDIM + d)) * Skv + k0 + kc;
    *(bf16x8*)dst = v0;
    *(bf16x8*)(dst + 8) = v1;
  }
}

// ---------------------------------------------------------------------------
// async global->LDS, 16B per lane
// ---------------------------------------------------------------------------
__device__ __forceinline__ void gll16(const bf16* g, bf16* l) {
  __builtin_amdgcn_global_load_lds(
      (const __attribute__((address_space(1))) unsigned*)g,
      (__attribute__((address_space(3))) unsigned*)l, 16, 0, 0);
}

// ---------------------------------------------------------------------------
// 128x128-tile GEMM, 3-buffer counted-vmcnt pipeline (T4) + LDS XOR swizzle.
// __launch_bounds__(256, 3): request >=3 waves/SIMD (= 3 blocks/CU for
// 256-thread blocks), capping VGPR at ~168 so LDS (48 KiB -> 3 blocks) is
// the binding limit, not registers.  Cross-block overlap (m114) is what
// hides each block's per-iter vmcnt/barrier window.
// ---------------------------------------------------------------------------
__global__ __launch_bounds__(256, 3) void gemm128(
    const bf16* __restrict__ A, int lda, const bf16* __restrict__ Bt, int ldb,
    const float* __restrict__ bias, const bf16* __restrict__ res_b,
    const float* __restrict__ res_f, bf16* __restrict__ out_b,
    float* __restrict__ out_f, int N, int K, int relu)
{
  __shared__ __align__(16) bf16 As[3][128 * 32];
  __shared__ __align__(16) bf16 Bs[3][128 * 32];
  const int tid  = threadIdx.x;
  const int lane = tid & 63, wave = tid >> 6;
  const int quad = lane >> 4, l16 = lane & 15;
  const int wm = wave & 1, wn = wave >> 1;

  const int gx   = gridDim.x;
  const int nwg  = gx * gridDim.y;
  const int flat = blockIdx.y * gx + blockIdx.x;
  const int wg   = (flat & 7) * (nwg >> 3) + (flat >> 3);   // bijective: nwg%8==0
  const int m0 = (wg / gx) * 128, n0 = (wg % gx) * 128;

  const int c0row = tid >> 2;
  const int c0kc  = (((tid & 3) ^ ((tid >> 2) & 3) ^ ((tid >> 4) & 3))) * 8;
  const int c1row = 64 + c0row;

  const int co = ((quad ^ ((l16 & 3) ^ ((l16 >> 2) & 3)))) * 8;

  const bf16* a0 = A  + (size_t)(m0 + c0row) * lda + c0kc;
  const bf16* b0 = Bt + (size_t)(n0 + c0row) * ldb + c0kc;
  const bf16* a1 = A  + (size_t)(m0 + c1row) * lda + c0kc;
  const bf16* b1 = Bt + (size_t)(n0 + c1row) * ldb + c0kc;

  f32x4 acc[4][4];
  #pragma unroll
  for (int i = 0; i < 4; ++i)
    #pragma unroll
    for (int j = 0; j < 4; ++j) acc[i][j] = f32x4{0, 0, 0, 0};

  auto stage = [&](int k0, int buf) {
    gll16(a0 + k0, As[buf] + wave * 512);
    gll16(b0 + k0, Bs[buf] + wave * 512);
    gll16(a1 + k0, As[buf] + 2048 + wave * 512);
    gll16(b1 + k0, Bs[buf] + 2048 + wave * 512);
  };

  const int nk = K >> 5;
  stage(0, 0);
  if (nk > 1) stage(32, 1);

  int cur = 0;
  for (int t = 0; t < nk; ++t) {
    if (t + 1 < nk) asm volatile("s_waitcnt vmcnt(4)" ::: "memory");
    else            asm volatile("s_waitcnt vmcnt(0)" ::: "memory");
    __builtin_amdgcn_s_barrier();
    __builtin_amdgcn_sched_barrier(0);

    bf16x8 af[4], bfr[4];
    #pragma unroll
    for (int i = 0; i < 4; ++i)
      af[i] = *(const bf16x8*)(As[cur] + (wm * 64 + i * 16 + l16) * 32 + co);
    #pragma unroll
    for (int j = 0; j < 4; ++j)
      bfr[j] = *(const bf16x8*)(Bs[cur] + (wn * 64 + j * 16 + l16) * 32 + co);
    #pragma unroll
    for (int i = 0; i < 4; ++i)
      #pragma unroll
      for (int j = 0; j < 4; ++j)
        acc[i][j] = __builtin_amdgcn_mfma_f32_16x16x32_bf16(af[i], bfr[j], acc[i][j], 0, 0, 0);

    if (t + 2 < nk) {
      int nb = cur + 2; if (nb >= 3) nb -= 3;
      stage((t + 2) << 5, nb);
    }
    cur = (cur + 1 == 3) ? 0 : cur + 1;
  }

  #pragma unroll
  for (int j = 0; j < 4; ++j) {
    const int col = n0 + wn * 64 + j * 16 + l16;
    const float bv = bias ? bias[col] : 0.f;
    #pragma unroll
    for (int i = 0; i < 4; ++i) {
      #pragma unroll
      for (int r = 0; r < 4; ++r) {
        const int row = m0 + wm * 64 + i * 16 + quad * 4 + r;
        const size_t idx = (size_t)row * N + col;
        float v = acc[i][j][r] + bv;
        if (res_b) v += (float)res_b[idx];
        if (res_f) v += res_f[idx];
        if (relu)  v = fmaxf(v, 0.f);
        if (out_b) out_b[idx] = (bf16)v;
        if (out_f) out_f[idx] = v;
      }
    }
  }
}

// ---------------------------------------------------------------------------
// LayerNorm over last dim (1024): fp32 in, fp32 params, bf16 and/or fp32 out.
// ---------------------------------------------------------------------------
__global__ __launch_bounds__(256) void ln_kernel(
    const float* __restrict__ x, const float* __restrict__ g, const float* __restrict__ b,
    bf16* __restrict__ out_b, float* __restrict__ out_f)
{
  __shared__ float red[8];
  const int tid = threadIdx.x, lane = tid & 63, wave = tid >> 6;
  const float* xr = x + (size_t)blockIdx.x * EMBED;
  float4 v = *(const float4*)(xr + tid * 4);
  float vv[4] = {v.x, v.y, v.z, v.w};
  float s  = vv[0] + vv[1] + vv[2] + vv[3];
  float s2 = vv[0]*vv[0] + vv[1]*vv[1] + vv[2]*vv[2] + vv[3]*vv[3];
  #pragma unroll
  for (int off = 32; off >= 1; off >>= 1) {
    s  += __shfl_xor(s, off);
    s2 += __shfl_xor(s2, off);
  }
  if (lane == 0) { red[wave] = s; red[4 + wave] = s2; }
  __syncthreads();
  s  = red[0] + red[1] + red[2] + red[3];
  s2 = red[4] + red[5] + red[6] + red[7];
  const float mu  = s * (1.f / EMBED);
  const float var = s2 * (1.f / EMBED) - mu * mu;
  const float rs  = rsqrtf(fmaxf(var, 0.f) + 1e-5f);
  #pragma unroll
  for (int i = 0; i < 4; ++i) {
    const int col = tid * 4 + i;
    const float o = (vv[i] - mu) * rs * g[col] + b[col];
    const size_t idx = (size_t)blockIdx.x * EMBED + col;
    if (out_b) out_b[idx] = (bf16)o;
    if (out_f) out_f[idx] = o;
  }
}

// ---------------------------------------------------------------------------
// MFMA flash attention (round-6 verified form).  Swapped QK^T (mfma(K,Q))
// => lane-local softmax.  K/V staged via global_load_lds (linear dest +
// swizzled source/read), double-buffered, prefetch-before-compute, one
// barrier per K-tile.  Raw-domain max, 1/sqrt(d) folded into exp via fma.
// Causal grid pairs q-tiles bx and 15-bx (load balance).
// ---------------------------------------------------------------------------
__global__ __launch_bounds__(256) void fattn_kernel(
    const bf16* __restrict__ Q, int ldq, const bf16* __restrict__ K, int ldk,
    const bf16* __restrict__ Vt, bf16* __restrict__ Y, int Skv, int causal)
{
  constexpr int PLD = 72;                       // P-buffer stride (conflict-free)
  __shared__ __align__(16) bf16 Ks[2][64 * 64]; // [key][d], swizzled
  __shared__ __align__(16) bf16 Vs[2][64 * 64]; // [d][key], swizzled
  __shared__ __align__(16) bf16 Ps[4 * 32 * PLD];

  const int tid  = threadIdx.x;
  const int lane = tid & 63, wave = tid >> 6;
  const int quad = lane >> 4, l16 = lane & 15;
  const int bh = blockIdx.y, b = bh >> 4, h = bh & 15;

  const bf16* Kb = K + (size_t)b * Skv * ldk + h * HDIM;
  const bf16* Vb = Vt + (size_t)(bh * HDIM) * Skv;

  const int sr = lane >> 3;
  const int se = ((lane & 7) ^ sr) << 3;        // swizzled source elem offset

  const int sw  = l16 & 7;
  const int co0 = (quad ^ sw) << 3;
  const int co1 = ((4 + quad) ^ sw) << 3;

  auto stage = [&](int kt, int buf) {
    const int k0 = kt * 64;
    const int r0 = wave * 16;
    gll16(Kb + (size_t)(k0 + r0 + sr) * ldk + se,     &Ks[buf][(r0)     * 64]);
    gll16(Kb + (size_t)(k0 + r0 + 8 + sr) * ldk + se, &Ks[buf][(r0 + 8) * 64]);
    gll16(Vb + (size_t)(r0 + sr) * Skv + k0 + se,     &Vs[buf][(r0)     * 64]);
    gll16(Vb + (size_t)(r0 + 8 + sr) * Skv + k0 + se, &Vs[buf][(r0 + 8) * 64]);
  };

  bf16* Pw = Ps + wave * 32 * PLD;
  const int npass = causal ? 2 : 1;

  for (int pass = 0; pass < npass; ++pass) {
    const int qt = causal ? (pass == 0 ? (int)blockIdx.x
                                       : (SEQ / 128 - 1 - (int)blockIdx.x))
                          : (int)blockIdx.x;
    const int q0  = qt * 128;
    const int wq0 = q0 + wave * 32;

    bf16x8 qf[2][2];
    #pragma unroll
    for (int i = 0; i < 2; ++i) {
      const bf16* qp = Q + (size_t)(b * SEQ + wq0 + i * 16 + l16) * ldq + h * HDIM;
      qf[i][0] = *(const bf16x8*)(qp + quad * 8);
      qf[i][1] = *(const bf16x8*)(qp + 32 + quad * 8);
    }

    f32x4 O[2][4];
    float m_run[2], l_run[2];
    #pragma unroll
    for (int i = 0; i < 2; ++i)
      #pragma unroll
      for (int nt = 0; nt < 4; ++nt) O[i][nt] = f32x4{0, 0, 0, 0};
    #pragma unroll
    for (int i = 0; i < 2; ++i) { m_run[i] = -1e30f; l_run[i] = 0.f; }

    const int nkt = causal ? (q0 / 64 + 2) : (Skv / 64);

    stage(0, 0);
    __syncthreads();

    for (int kt = 0; kt < nkt; ++kt) {
      const int cur = kt & 1;
      const int k0 = kt * 64;
      if (kt + 1 < nkt) stage(kt + 1, cur ^ 1);

      const bf16* Kc = Ks[cur];
      const bf16* Vc = Vs[cur];

      // ---- S^T = K Q^T  (col=l16 -> q, row=quad*4+r -> key), raw (unscaled)
      f32x4 s[2][4];
      __builtin_amdgcn_s_setprio(1);
      #pragma unroll
      for (int nt = 0; nt < 4; ++nt) {
        const int row = nt * 16 + l16;
        bf16x8 kf0 = *(const bf16x8*)(Kc + row * 64 + co0);
        bf16x8 kf1 = *(const bf16x8*)(Kc + row * 64 + co1);
        #pragma unroll
        for (int i = 0; i < 2; ++i) {
          f32x4 t = f32x4{0, 0, 0, 0};
          t = __builtin_amdgcn_mfma_f32_16x16x32_bf16(kf0, qf[i][0], t, 0, 0, 0);
          t = __builtin_amdgcn_mfma_f32_16x16x32_bf16(kf1, qf[i][1], t, 0, 0, 0);
          s[i][nt] = t;
        }
      }
      __builtin_amdgcn_s_setprio(0);

      if (causal && (k0 + 63 > wq0)) {          // mask only on diagonal tiles
        #pragma unroll
        for (int i = 0; i < 2; ++i) {
          const int q = wq0 + i * 16 + l16;
          #pragma unroll
          for (int nt = 0; nt < 4; ++nt) {
            #pragma unroll
            for (int r = 0; r < 4; ++r) {
              const int key = k0 + nt * 16 + quad * 4 + r;
              if (key > q) s[i][nt][r] = -1e30f;
            }
          }
        }
      }

      // ---- online softmax: raw-domain max, scale folded into exp via fma
      #pragma unroll
      for (int i = 0; i < 2; ++i) {
        float pm = s[i][0][0];
        #pragma unroll
        for (int nt = 0; nt < 4; ++nt)
          #pragma unroll
          for (int r = 0; r < 4; ++r) pm = fmaxf(pm, s[i][nt][r]);
        pm = fmaxf(pm, __shfl_xor(pm, 16));
        pm = fmaxf(pm, __shfl_xor(pm, 32));
        const float m_new = fmaxf(m_run[i], pm);
        const float al = __expf((m_run[i] - m_new) * 0.125f);
        m_run[i] = m_new;
        const float mc = m_new * 0.125f;
        float ls = 0.f;
        #pragma unroll
        for (int nt = 0; nt < 4; ++nt) {
          #pragma unroll
          for (int r = 0; r < 4; ++r) {
            const float e = __expf(fmaf(s[i][nt][r], 0.125f, -mc));
            s[i][nt][r] = e;
            ls += e;
          }
        }
        ls += __shfl_xor(ls, 16);
        ls += __shfl_xor(ls, 32);
        l_run[i] = l_run[i] * al + ls;
        // P store: row q=i*16+l16, keys nt*16+quad*4..+3 contiguous -> b64
        #pragma unroll
        for (int nt = 0; nt < 4; ++nt) {
          bf16x4 pk;
          pk[0] = (bf16)s[i][nt][0]; pk[1] = (bf16)s[i][nt][1];
          pk[2] = (bf16)s[i][nt][2]; pk[3] = (bf16)s[i][nt][3];
          *(bf16x4*)(Pw + (i * 16 + l16) * PLD + nt * 16 + quad * 4) = pk;
        }
        // O rescale: O rows are quad*4+r -> pull al from lane (quad*4+r)
        float alo[4];
        #pragma unroll
        for (int r = 0; r < 4; ++r) alo[r] = __shfl(al, quad * 4 + r);
        #pragma unroll
        for (int nt = 0; nt < 4; ++nt)
          #pragma unroll
          for (int r = 0; r < 4; ++r) O[i][nt][r] *= alo[r];
      }

      // ---- O += P V ----
      bf16x8 pf[2][2];
      #pragma unroll
      for (int i = 0; i < 2; ++i) {
        pf[i][0] = *(const bf16x8*)(Pw + (i * 16 + l16) * PLD + quad * 8);
        pf[i][1] = *(const bf16x8*)(Pw + (i * 16 + l16) * PLD + 32 + quad * 8);
      }
      __builtin_amdgcn_s_setprio(1);
      #pragma unroll
      for (int nt = 0; nt < 4; ++nt) {
        const int row = nt * 16 + l16;
        bf16x8 vf0 = *(const bf16x8*)(Vc + row * 64 + co0);
        bf16x8 vf1 = *(const bf16x8*)(Vc + row * 64 + co1);
        #pragma unroll
        for (int i = 0; i < 2; ++i) {
          O[i][nt] = __builtin_amdgcn_mfma_f32_16x16x32_bf16(pf[i][0], vf0, O[i][nt], 0, 0, 0);
          O[i][nt] = __builtin_amdgcn_mfma_f32_16x16x32_bf16(pf[i][1], vf1, O[i][nt], 0, 0, 0);
        }
      }
      __builtin_amdgcn_s_setprio(0);
      __syncthreads();
    }

    #pragma unroll
    for (int i = 0; i < 2; ++i) {
      float inv[4];
      #pragma unroll
      for (int r = 0; r < 4; ++r) {
        const float lv = __shfl(l_run[i], quad * 4 + r);
        inv[r] = 1.f / lv;
      }
      #pragma unroll
      for (int nt = 0; nt < 4; ++nt) {
        #pragma unroll
        for (int r = 0; r < 4; ++r) {
          const int q = wq0 + i * 16 + quad * 4 + r;
          Y[((size_t)(b * SEQ + q)) * EMBED + h * HDIM + nt * 16 + l16] = (bf16)(O[i][nt][r] * inv[r]);
        }
      }
    }
  }
}

__global__ void fill_kernel(float* out, float v, int n) {
  int i = blockIdx.x * 256 + threadIdx.x;
  if (i < n) out[i] = v;
}

// ---------------------------------------------------------------------------
extern "C" void kernel_launch(void* const* d_in, const int* in_sizes, int n_in,
                              void* d_out, int out_size, void* d_ws, size_t ws_size,
                              hipStream_t stream)
{
  const float* tgt    = (const float*)d_in[0];
  const float* mem    = (const float*)d_in[1];
  const float* sa_Wq  = (const float*)d_in[3];
  const float* sa_Wqb = (const float*)d_in[4];
  const float* sa_Wk  = (const float*)d_in[5];
  const float* sa_Wkb = (const float*)d_in[6];
  const float* sa_Wv  = (const float*)d_in[7];
  const float* sa_Wvb = (const float*)d_in[8];
  const float* sa_A   = (const float*)d_in[9];
  const float* sa_Ab  = (const float*)d_in[10];
  const float* ca_Wq  = (const float*)d_in[11];
  const float* ca_Wqb = (const float*)d_in[12];
  const float* ca_Wk  = (const float*)d_in[13];
  const float* ca_Wkb = (const float*)d_in[14];
  const float* ca_Wv  = (const float*)d_in[15];
  const float* ca_Wvb = (const float*)d_in[16];
  const float* ca_A   = (const float*)d_in[17];
  const float* ca_Ab  = (const float*)d_in[18];
  const float* l1W    = (const float*)d_in[19];
  const float* l1b    = (const float*)d_in[20];
  const float* l2W    = (const float*)d_in[21];
  const float* l2b    = (const float*)d_in[22];
  const float* g1     = (const float*)d_in[23];
  const float* b1     = (const float*)d_in[24];
  const float* g2     = (const float*)d_in[25];
  const float* b2     = (const float*)d_in[26];
  const float* g3     = (const float*)d_in[27];
  const float* b3     = (const float*)d_in[28];

  const size_t MB = 1024 * 1024;
  const size_t NEED = 80 * MB + 4096;
  if (ws_size < NEED) {
    fill_kernel<<<(out_size + 255) / 256, 256, 0, stream>>>((float*)d_out, 3.0f, out_size);
    return;
  }

  char* ws = (char*)d_ws;
  const size_t MD = (size_t)MROWS * EMBED;       // 8M elements
  // phase A
  bf16*  qkv   = (bf16*)ws;                      // [8192][3072] 48 MB
  bf16*  yb    = (bf16*)(ws + 48 * MB);          // 16 MB attention output
  bf16*  wqkvt = (bf16*)(ws + 48 * MB);          // 6 MB weights (dead before fattn writes yb)
  float* qkvbias = (float*)(ws + 54 * MB + 512 * 1024);
  // phase B
  bf16*  kvb   = (bf16*)ws;                      // [8192][2048] 32 MB
  bf16*  qB    = (bf16*)(ws + 32 * MB);          // 16 MB
  bf16*  wkvt  = (bf16*)(ws + 48 * MB);          // 4 MB
  bf16*  wqt   = (bf16*)(ws + 52 * MB);          // 2 MB
  float* kvbias = (float*)(ws + 54 * MB + 512 * 1024);
  // shared
  bf16*  awt   = (bf16*)ws;                      // 2 MB out-proj Wt (qkv/kvb dead)
  bf16*  xb    = (bf16*)(ws + 64 * MB);          // 16 MB LN output stream
  // phase C
  bf16*  hb    = (bf16*)ws;                      // [8192][2048] 32 MB hidden half
  bf16*  l1t   = (bf16*)(ws + 32 * MB);          // 8 MB
  bf16*  l2t   = (bf16*)(ws + 40 * MB);          // 8 MB
  // d_out regions
  float* P   = (float*)d_out;                    // fp32 pre-LN scratch (32 MB)
  bf16*  inb = (bf16*)d_out;                     // converted tgt/mem (16 MB)
  bf16*  vtg = (bf16*)((char*)d_out + 16 * MB);  // V^T for attention (16 MB)

  dim3 blk(256);
  dim3 gQKV(3072 / 128, MROWS / 128);   // (24,64)
  dim3 gKV(2048 / 128, MROWS / 128);    // (16,64)
  dim3 gEE(EMBED / 128, MROWS / 128);   // (8,64)
  dim3 gF1(2048 / 128, MROWS / 128);    // (16,64)
  dim3 gATC(SEQ / 256, BATCH * HEADS);  // (8,64)  causal: paired q-tiles
  dim3 gAT(SEQ / 128, BATCH * HEADS);   // (16,64) cross
  dim3 gVT(SEQ / 64, BATCH * HEADS);    // (32,64)
  dim3 gWee(16, 16);
  const int ncv = (int)(MD / 8 / 256);

  // ---- Phase A: self-attention ----
  cvt_kernel<<<ncv, blk, 0, stream>>>(tgt, inb, (int)MD);
  wt_kernel<<<gWee, blk, 0, stream>>>(sa_Wq, wqkvt, EMBED, EMBED);
  wt_kernel<<<gWee, blk, 0, stream>>>(sa_Wk, wqkvt + 1024 * 1024, EMBED, EMBED);
  wt_kernel<<<gWee, blk, 0, stream>>>(sa_Wv, wqkvt + 2 * 1024 * 1024, EMBED, EMBED);
  cat3_kernel<<<12, blk, 0, stream>>>(qkvbias, sa_Wqb, sa_Wkb, sa_Wvb, EMBED);
  gemm128<<<gQKV, blk, 0, stream>>>(inb, EMBED, wqkvt, EMBED, qkvbias, nullptr, nullptr, qkv, nullptr, 3072, EMBED, 0);
  vtr_kernel<<<gVT, blk, 0, stream>>>(qkv + 2048, 3072, vtg, SEQ);
  fattn_kernel<<<gATC, blk, 0, stream>>>(qkv, 3072, qkv + 1024, 3072, vtg, yb, SEQ, 1);
  wt_kernel<<<gWee, blk, 0, stream>>>(sa_A, awt, EMBED, EMBED);
  gemm128<<<gEE, blk, 0, stream>>>(yb, EMBED, awt, EMBED, sa_Ab, nullptr, tgt, nullptr, P, EMBED, EMBED, 0);
  ln_kernel<<<MROWS, blk, 0, stream>>>(P, g1, b1, xb, nullptr);

  // ---- Phase B: cross-attention ----
  cvt_kernel<<<ncv, blk, 0, stream>>>(mem, inb, (int)MD);
  wt_kernel<<<gWee, blk, 0, stream>>>(ca_Wk, wkvt, EMBED, EMBED);
  wt_kernel<<<gWee, blk, 0, stream>>>(ca_Wv, wkvt + 1024 * 1024, EMBED, EMBED);
  wt_kernel<<<gWee, blk, 0, stream>>>(ca_Wq, wqt, EMBED, EMBED);
  cat3_kernel<<<8, blk, 0, stream>>>(kvbias, ca_Wkb, ca_Wvb, nullptr, EMBED);
  gemm128<<<gKV, blk, 0, stream>>>(inb, EMBED, wkvt, EMBED, kvbias, nullptr, nullptr, kvb, nullptr, 2048, EMBED, 0);
  gemm128<<<gEE, blk, 0, stream>>>(xb, EMBED, wqt, EMBED, ca_Wqb, nullptr, nullptr, qB, nullptr, EMBED, EMBED, 0);
  vtr_kernel<<<gVT, blk, 0, stream>>>(kvb + 1024, 2048, vtg, SEQ);
  fattn_kernel<<<gAT, blk, 0, stream>>>(qB, 1024, kvb, 2048, vtg, yb, SEQ, 0);
  wt_kernel<<<gWee, blk, 0, stream>>>(ca_A, awt, EMBED, EMBED);
  gemm128<<<gEE, blk, 0, stream>>>(yb, EMBED, awt, EMBED, ca_Ab, xb, nullptr, nullptr, P, EMBED, EMBED, 0);
  ln_kernel<<<MROWS, blk, 0, stream>>>(P, g2, b2, xb, nullptr);

  // ---- Phase C: FFN (split-K over DFF halves) ----
  wt_kernel<<<dim3(16, 64), blk, 0, stream>>>(l1W, l1t, EMBED, DFF);
  wt_kernel<<<dim3(64, 16), blk, 0, stream>>>(l2W, l2t, DFF, EMBED);
  gemm128<<<gF1, blk, 0, stream>>>(xb, EMBED, l1t, EMBED, l1b, nullptr, nullptr, hb, nullptr, 2048, EMBED, 1);
  gemm128<<<gEE, blk, 0, stream>>>(hb, 2048, l2t, DFF, l2b, xb, nullptr, nullptr, P, EMBED, 2048, 0);
  gemm128<<<gF1, blk, 0, stream>>>(xb, EMBED, l1t + (size_t)2048 * 1024, EMBED, l1b + 2048, nullptr, nullptr, hb, nullptr, 2048, EMBED, 1);
  gemm128<<<gEE, blk, 0, stream>>>(hb, 2048, l2t + 2048, DFF, nullptr, nullptr, P, nullptr, P, EMBED, 2048, 0);
  ln_kernel<<<MROWS, blk, 0, stream>>>(P, g3, b3, nullptr, (float*)d_out);
}

// Round 11
// 1049.421 us; speedup vs baseline: 1.1012x; 1.0569x over previous
//
#include <hip/hip_runtime.h>

typedef __bf16 bf16;
typedef __bf16 bf16x4 __attribute__((ext_vector_type(4)));
typedef __bf16 bf16x8 __attribute__((ext_vector_type(8)));
typedef float  f32x4  __attribute__((ext_vector_type(4)));

#define EMBED 1024
#define HEADS 16
#define HDIM  64
#define DFF   4096
#define BATCH 4
#define SEQ   2048
#define MROWS 8192   // BATCH*SEQ

// ---------------------------------------------------------------------------
// fp32 -> bf16 elementwise convert (n multiple of 8)
// ---------------------------------------------------------------------------
__global__ __launch_bounds__(256) void cvt_kernel(
    const float* __restrict__ x, bf16* __restrict__ y, int n)
{
  int i = (blockIdx.x * 256 + threadIdx.x) * 8;
  if (i >= n) return;
  float4 a = *(const float4*)(x + i);
  float4 b = *(const float4*)(x + i + 4);
  bf16x8 v;
  v[0] = (bf16)a.x; v[1] = (bf16)a.y; v[2] = (bf16)a.z; v[3] = (bf16)a.w;
  v[4] = (bf16)b.x; v[5] = (bf16)b.y; v[6] = (bf16)b.z; v[7] = (bf16)b.w;
  *(bf16x8*)(y + i) = v;
}

// ---------------------------------------------------------------------------
// Weight transpose-convert: W[K][N] fp32 -> Wt[N][K] bf16. 64x64 tile via LDS.
// ---------------------------------------------------------------------------
__global__ __launch_bounds__(256) void wt_kernel(
    const float* __restrict__ W, bf16* __restrict__ Wt, int K, int N)
{
  __shared__ __align__(16) float Ls[64 * 68];
  const int k0 = blockIdx.x * 64, n0 = blockIdx.y * 64;
  const int ty = threadIdx.x >> 4, tx = threadIdx.x & 15;
  #pragma unroll
  for (int r = 0; r < 4; ++r) {
    const int k = ty + r * 16;
    float4 v = *(const float4*)(W + (size_t)(k0 + k) * N + n0 + tx * 4);
    *(float4*)(Ls + k * 68 + tx * 4) = v;
  }
  __syncthreads();
  #pragma unroll
  for (int it = 0; it < 2; ++it) {
    const int c = it * 256 + threadIdx.x;
    const int n = c >> 3, kc = (c & 7) * 8;
    bf16x8 v;
    #pragma unroll
    for (int j = 0; j < 8; ++j) v[j] = (bf16)Ls[(kc + j) * 68 + n];
    *(bf16x8*)(Wt + (size_t)(n0 + n) * K + k0 + kc) = v;
  }
}

// ---------------------------------------------------------------------------
// bias concat: dst[0:n)=a, [n:2n)=b, [2n:3n)=c (c optional)
// ---------------------------------------------------------------------------
__global__ void cat3_kernel(float* __restrict__ dst, const float* __restrict__ a,
                            const float* __restrict__ b, const float* __restrict__ c, int n)
{
  int i = blockIdx.x * 256 + threadIdx.x;
  if (i < n) dst[i] = a[i];
  else if (i < 2 * n) dst[i] = b[i - n];
  else if (c && i < 3 * n) dst[i] = c[i - 2 * n];
}

// ---------------------------------------------------------------------------
// V transpose for attention: V[(b*Skv+key)*ldv + h*64 + d] ->
// Vt[((b*16+h)*64 + d)*Skv + key].  64key x 64d tile via LDS.
// ---------------------------------------------------------------------------
__global__ __launch_bounds__(256) void vtr_kernel(
    const bf16* __restrict__ V, int ldv, bf16* __restrict__ Vt, int Skv)
{
  __shared__ __align__(16) bf16 Ls[64 * 72];
  const int k0 = blockIdx.x * 64;
  const int bh = blockIdx.y, b = bh >> 4, h = bh & 15;
  const int t = threadIdx.x;
  {
    const int key = t >> 2, dc = (t & 3) * 16;
    const bf16* src = V + (size_t)(b * Skv + k0 + key) * ldv + h * HDIM + dc;
    bf16x8 a0 = *(const bf16x8*)src;
    bf16x8 a1 = *(const bf16x8*)(src + 8);
    *(bf16x8*)(Ls + key * 72 + dc) = a0;
    *(bf16x8*)(Ls + key * 72 + dc + 8) = a1;
  }
  __syncthreads();
  {
    const int d = t >> 2, kc = (t & 3) * 16;
    bf16x8 v0, v1;
    #pragma unroll
    for (int j = 0; j < 8; ++j) v0[j] = Ls[(kc + j) * 72 + d];
    #pragma unroll
    for (int j = 0; j < 8; ++j) v1[j] = Ls[(kc + 8 + j) * 72 + d];
    bf16* dst = Vt + ((size_t)(bh * HDIM + d)) * Skv + k0 + kc;
    *(bf16x8*)dst = v0;
    *(bf16x8*)(dst + 8) = v1;
  }
}

// ---------------------------------------------------------------------------
// async global->LDS, 16B per lane
// ---------------------------------------------------------------------------
__device__ __forceinline__ void gll16(const bf16* g, bf16* l) {
  __builtin_amdgcn_global_load_lds(
      (const __attribute__((address_space(1))) unsigned*)g,
      (__attribute__((address_space(3))) unsigned*)l, 16, 0, 0);
}

// ---------------------------------------------------------------------------
// 128x128-tile GEMM, 3-buffer counted-vmcnt pipeline (T4) + LDS XOR swizzle.
// Round-8 verified form (no min-waves hint: capping VGPR at 168 caused
// spills, round 10 — let the allocator breathe; LDS 48 KiB bounds 3 blk/CU).
// ---------------------------------------------------------------------------
__global__ __launch_bounds__(256) void gemm128(
    const bf16* __restrict__ A, int lda, const bf16* __restrict__ Bt, int ldb,
    const float* __restrict__ bias, const bf16* __restrict__ res_b,
    const float* __restrict__ res_f, bf16* __restrict__ out_b,
    float* __restrict__ out_f, int N, int K, int relu)
{
  __shared__ __align__(16) bf16 As[3][128 * 32];
  __shared__ __align__(16) bf16 Bs[3][128 * 32];
  const int tid  = threadIdx.x;
  const int lane = tid & 63, wave = tid >> 6;
  const int quad = lane >> 4, l16 = lane & 15;
  const int wm = wave & 1, wn = wave >> 1;

  const int gx   = gridDim.x;
  const int nwg  = gx * gridDim.y;
  const int flat = blockIdx.y * gx + blockIdx.x;
  const int wg   = (flat & 7) * (nwg >> 3) + (flat >> 3);   // bijective: nwg%8==0
  const int m0 = (wg / gx) * 128, n0 = (wg % gx) * 128;

  const int c0row = tid >> 2;
  const int c0kc  = (((tid & 3) ^ ((tid >> 2) & 3) ^ ((tid >> 4) & 3))) * 8;
  const int c1row = 64 + c0row;

  const int co = ((quad ^ ((l16 & 3) ^ ((l16 >> 2) & 3)))) * 8;

  const bf16* a0 = A  + (size_t)(m0 + c0row) * lda + c0kc;
  const bf16* b0 = Bt + (size_t)(n0 + c0row) * ldb + c0kc;
  const bf16* a1 = A  + (size_t)(m0 + c1row) * lda + c0kc;
  const bf16* b1 = Bt + (size_t)(n0 + c1row) * ldb + c0kc;

  f32x4 acc[4][4];
  #pragma unroll
  for (int i = 0; i < 4; ++i)
    #pragma unroll
    for (int j = 0; j < 4; ++j) acc[i][j] = f32x4{0, 0, 0, 0};

  auto stage = [&](int k0, int buf) {
    gll16(a0 + k0, As[buf] + wave * 512);
    gll16(b0 + k0, Bs[buf] + wave * 512);
    gll16(a1 + k0, As[buf] + 2048 + wave * 512);
    gll16(b1 + k0, Bs[buf] + 2048 + wave * 512);
  };

  const int nk = K >> 5;
  stage(0, 0);
  if (nk > 1) stage(32, 1);

  int cur = 0;
  for (int t = 0; t < nk; ++t) {
    if (t + 1 < nk) asm volatile("s_waitcnt vmcnt(4)" ::: "memory");
    else            asm volatile("s_waitcnt vmcnt(0)" ::: "memory");
    __builtin_amdgcn_s_barrier();
    __builtin_amdgcn_sched_barrier(0);

    bf16x8 af[4], bfr[4];
    #pragma unroll
    for (int i = 0; i < 4; ++i)
      af[i] = *(const bf16x8*)(As[cur] + (wm * 64 + i * 16 + l16) * 32 + co);
    #pragma unroll
    for (int j = 0; j < 4; ++j)
      bfr[j] = *(const bf16x8*)(Bs[cur] + (wn * 64 + j * 16 + l16) * 32 + co);
    #pragma unroll
    for (int i = 0; i < 4; ++i)
      #pragma unroll
      for (int j = 0; j < 4; ++j)
        acc[i][j] = __builtin_amdgcn_mfma_f32_16x16x32_bf16(af[i], bfr[j], acc[i][j], 0, 0, 0);

    if (t + 2 < nk) {
      int nb = cur + 2; if (nb >= 3) nb -= 3;
      stage((t + 2) << 5, nb);
    }
    cur = (cur + 1 == 3) ? 0 : cur + 1;
  }

  #pragma unroll
  for (int j = 0; j < 4; ++j) {
    const int col = n0 + wn * 64 + j * 16 + l16;
    const float bv = bias ? bias[col] : 0.f;
    #pragma unroll
    for (int i = 0; i < 4; ++i) {
      #pragma unroll
      for (int r = 0; r < 4; ++r) {
        const int row = m0 + wm * 64 + i * 16 + quad * 4 + r;
        const size_t idx = (size_t)row * N + col;
        float v = acc[i][j][r] + bv;
        if (res_b) v += (float)res_b[idx];
        if (res_f) v += res_f[idx];
        if (relu)  v = fmaxf(v, 0.f);
        if (out_b) out_b[idx] = (bf16)v;
        if (out_f) out_f[idx] = v;
      }
    }
  }
}

// ---------------------------------------------------------------------------
// LayerNorm over last dim (1024): fp32 in, fp32 params, bf16 and/or fp32 out.
// ---------------------------------------------------------------------------
__global__ __launch_bounds__(256) void ln_kernel(
    const float* __restrict__ x, const float* __restrict__ g, const float* __restrict__ b,
    bf16* __restrict__ out_b, float* __restrict__ out_f)
{
  __shared__ float red[8];
  const int tid = threadIdx.x, lane = tid & 63, wave = tid >> 6;
  const float* xr = x + (size_t)blockIdx.x * EMBED;
  float4 v = *(const float4*)(xr + tid * 4);
  float vv[4] = {v.x, v.y, v.z, v.w};
  float s  = vv[0] + vv[1] + vv[2] + vv[3];
  float s2 = vv[0]*vv[0] + vv[1]*vv[1] + vv[2]*vv[2] + vv[3]*vv[3];
  #pragma unroll
  for (int off = 32; off >= 1; off >>= 1) {
    s  += __shfl_xor(s, off);
    s2 += __shfl_xor(s2, off);
  }
  if (lane == 0) { red[wave] = s; red[4 + wave] = s2; }
  __syncthreads();
  s  = red[0] + red[1] + red[2] + red[3];
  s2 = red[4] + red[5] + red[6] + red[7];
  const float mu  = s * (1.f / EMBED);
  const float var = s2 * (1.f / EMBED) - mu * mu;
  const float rs  = rsqrtf(fmaxf(var, 0.f) + 1e-5f);
  #pragma unroll
  for (int i = 0; i < 4; ++i) {
    const int col = tid * 4 + i;
    const float o = (vv[i] - mu) * rs * g[col] + b[col];
    const size_t idx = (size_t)blockIdx.x * EMBED + col;
    if (out_b) out_b[idx] = (bf16)o;
    if (out_f) out_f[idx] = o;
  }
}

// ---------------------------------------------------------------------------
// MFMA flash attention.  Swapped QK^T (mfma(K,Q)) => lane-local softmax.
// NEW: transposed PV (mfma(V,P)) => O^T (col=l16->q, reg=quad*4+r->d).
// A- and B-fragment lane layouts are identical, so the swap needs ZERO
// data-movement changes — but the softmax state (m,l,al), indexed (i,l16)
// and quad-uniform, becomes lane-local for O rescale and 1/l division
// (deletes all al/l shuffles), and the Y epilogue becomes coalesced bf16x4
// stores instead of 32 scalar stores per lane.  exp via native exp2 with
// 1/sqrt(d)*log2e folded into one fma (isolated from round-5's defer-max).
// K/V staged via global_load_lds (linear dest + swizzled source/read),
// double-buffered, prefetch-before-compute, one barrier per K-tile.
// Causal grid pairs q-tiles bx and 15-bx (load balance).
// ---------------------------------------------------------------------------
__global__ __launch_bounds__(256) void fattn_kernel(
    const bf16* __restrict__ Q, int ldq, const bf16* __restrict__ K, int ldk,
    const bf16* __restrict__ Vt, bf16* __restrict__ Y, int Skv, int causal)
{
  constexpr int PLD = 72;                       // P-buffer stride (conflict-free)
  constexpr float CE = 0.18033688011f;          // 0.125 * log2(e)
  __shared__ __align__(16) bf16 Ks[2][64 * 64]; // [key][d], swizzled
  __shared__ __align__(16) bf16 Vs[2][64 * 64]; // [d][key], swizzled
  __shared__ __align__(16) bf16 Ps[4 * 32 * PLD];

  const int tid  = threadIdx.x;
  const int lane = tid & 63, wave = tid >> 6;
  const int quad = lane >> 4, l16 = lane & 15;
  const int bh = blockIdx.y, b = bh >> 4, h = bh & 15;

  const bf16* Kb = K + (size_t)b * Skv * ldk + h * HDIM;
  const bf16* Vb = Vt + (size_t)(bh * HDIM) * Skv;

  const int sr = lane >> 3;
  const int se = ((lane & 7) ^ sr) << 3;        // swizzled source elem offset

  const int sw  = l16 & 7;
  const int co0 = (quad ^ sw) << 3;
  const int co1 = ((4 + quad) ^ sw) << 3;

  auto stage = [&](int kt, int buf) {
    const int k0 = kt * 64;
    const int r0 = wave * 16;
    gll16(Kb + (size_t)(k0 + r0 + sr) * ldk + se,     &Ks[buf][(r0)     * 64]);
    gll16(Kb + (size_t)(k0 + r0 + 8 + sr) * ldk + se, &Ks[buf][(r0 + 8) * 64]);
    gll16(Vb + (size_t)(r0 + sr) * Skv + k0 + se,     &Vs[buf][(r0)     * 64]);
    gll16(Vb + (size_t)(r0 + 8 + sr) * Skv + k0 + se, &Vs[buf][(r0 + 8) * 64]);
  };

  bf16* Pw = Ps + wave * 32 * PLD;
  const int npass = causal ? 2 : 1;

  for (int pass = 0; pass < npass; ++pass) {
    const int qt = causal ? (pass == 0 ? (int)blockIdx.x
                                       : (SEQ / 128 - 1 - (int)blockIdx.x))
                          : (int)blockIdx.x;
    const int q0  = qt * 128;
    const int wq0 = q0 + wave * 32;

    bf16x8 qf[2][2];
    #pragma unroll
    for (int i = 0; i < 2; ++i) {
      const bf16* qp = Q + (size_t)(b * SEQ + wq0 + i * 16 + l16) * ldq + h * HDIM;
      qf[i][0] = *(const bf16x8*)(qp + quad * 8);
      qf[i][1] = *(const bf16x8*)(qp + 32 + quad * 8);
    }

    f32x4 O[2][4];                              // O^T: [i][d-tile nt], col=q
    float m_run[2], l_run[2];
    #pragma unroll
    for (int i = 0; i < 2; ++i)
      #pragma unroll
      for (int nt = 0; nt < 4; ++nt) O[i][nt] = f32x4{0, 0, 0, 0};
    #pragma unroll
    for (int i = 0; i < 2; ++i) { m_run[i] = -1e30f; l_run[i] = 0.f; }

    const int nkt = causal ? (q0 / 64 + 2) : (Skv / 64);

    stage(0, 0);
    __syncthreads();

    for (int kt = 0; kt < nkt; ++kt) {
      const int cur = kt & 1;
      const int k0 = kt * 64;
      if (kt + 1 < nkt) stage(kt + 1, cur ^ 1);

      const bf16* Kc = Ks[cur];
      const bf16* Vc = Vs[cur];

      // ---- S^T = K Q^T  (col=l16 -> q, row=quad*4+r -> key), raw (unscaled)
      f32x4 s[2][4];
      __builtin_amdgcn_s_setprio(1);
      #pragma unroll
      for (int nt = 0; nt < 4; ++nt) {
        const int row = nt * 16 + l16;
        bf16x8 kf0 = *(const bf16x8*)(Kc + row * 64 + co0);
        bf16x8 kf1 = *(const bf16x8*)(Kc + row * 64 + co1);
        #pragma unroll
        for (int i = 0; i < 2; ++i) {
          f32x4 t = f32x4{0, 0, 0, 0};
          t = __builtin_amdgcn_mfma_f32_16x16x32_bf16(kf0, qf[i][0], t, 0, 0, 0);
          t = __builtin_amdgcn_mfma_f32_16x16x32_bf16(kf1, qf[i][1], t, 0, 0, 0);
          s[i][nt] = t;
        }
      }
      __builtin_amdgcn_s_setprio(0);

      if (causal && (k0 + 63 > wq0)) {          // mask only on diagonal tiles
        #pragma unroll
        for (int i = 0; i < 2; ++i) {
          const int q = wq0 + i * 16 + l16;
          #pragma unroll
          for (int nt = 0; nt < 4; ++nt) {
            #pragma unroll
            for (int r = 0; r < 4; ++r) {
              const int key = k0 + nt * 16 + quad * 4 + r;
              if (key > q) s[i][nt][r] = -1e30f;
            }
          }
        }
      }

      // ---- online softmax: raw-domain max, native exp2 (scale*log2e in fma)
      #pragma unroll
      for (int i = 0; i < 2; ++i) {
        float pm = s[i][0][0];
        #pragma unroll
        for (int nt = 0; nt < 4; ++nt)
          #pragma unroll
          for (int r = 0; r < 4; ++r) pm = fmaxf(pm, s[i][nt][r]);
        pm = fmaxf(pm, __shfl_xor(pm, 16));
        pm = fmaxf(pm, __shfl_xor(pm, 32));
        const float m_new = fmaxf(m_run[i], pm);
        const float al = exp2f((m_run[i] - m_new) * CE);
        m_run[i] = m_new;
        const float mc = m_new * CE;
        float ls = 0.f;
        #pragma unroll
        for (int nt = 0; nt < 4; ++nt) {
          #pragma unroll
          for (int r = 0; r < 4; ++r) {
            const float e = exp2f(fmaf(s[i][nt][r], CE, -mc));
            s[i][nt][r] = e;
            ls += e;
          }
        }
        ls += __shfl_xor(ls, 16);
        ls += __shfl_xor(ls, 32);
        l_run[i] = l_run[i] * al + ls;
        // P store: row q=i*16+l16, keys nt*16+quad*4..+3 contiguous -> b64
        #pragma unroll
        for (int nt = 0; nt < 4; ++nt) {
          bf16x4 pk;
          pk[0] = (bf16)s[i][nt][0]; pk[1] = (bf16)s[i][nt][1];
          pk[2] = (bf16)s[i][nt][2]; pk[3] = (bf16)s[i][nt][3];
          *(bf16x4*)(Pw + (i * 16 + l16) * PLD + nt * 16 + quad * 4) = pk;
        }
        // O^T rescale: this lane's O[i][*] all have q = i*16+l16 -> al is
        // lane-local (quad-uniform softmax state).  No shuffles.
        #pragma unroll
        for (int nt = 0; nt < 4; ++nt)
          #pragma unroll
          for (int r = 0; r < 4; ++r) O[i][nt][r] *= al;
      }

      // ---- O^T += V^T P^T : mfma(vf, pf) — identical frag reads, swapped
      bf16x8 pf[2][2];
      #pragma unroll
      for (int i = 0; i < 2; ++i) {
        pf[i][0] = *(const bf16x8*)(Pw + (i * 16 + l16) * PLD + quad * 8);
        pf[i][1] = *(const bf16x8*)(Pw + (i * 16 + l16) * PLD + 32 + quad * 8);
      }
      __builtin_amdgcn_s_setprio(1);
      #pragma unroll
      for (int nt = 0; nt < 4; ++nt) {
        const int row = nt * 16 + l16;
        bf16x8 vf0 = *(const bf16x8*)(Vc + row * 64 + co0);
        bf16x8 vf1 = *(const bf16x8*)(Vc + row * 64 + co1);
        #pragma unroll
        for (int i = 0; i < 2; ++i) {
          O[i][nt] = __builtin_amdgcn_mfma_f32_16x16x32_bf16(vf0, pf[i][0], O[i][nt], 0, 0, 0);
          O[i][nt] = __builtin_amdgcn_mfma_f32_16x16x32_bf16(vf1, pf[i][1], O[i][nt], 0, 0, 0);
        }
      }
      __builtin_amdgcn_s_setprio(0);
      __syncthreads();
    }

    // ---- epilogue: O^T[d=nt*16+quad*4+r][q=i*16+l16]; inv lane-local;
    //      per (i,nt) a contiguous bf16x4 at d-offset nt*16+quad*4.
    #pragma unroll
    for (int i = 0; i < 2; ++i) {
      const float inv = 1.f / l_run[i];
      bf16* yq = Y + ((size_t)(b * SEQ + wq0 + i * 16 + l16)) * EMBED + h * HDIM;
      #pragma unroll
      for (int nt = 0; nt < 4; ++nt) {
        bf16x4 ov;
        #pragma unroll
        for (int r = 0; r < 4; ++r) ov[r] = (bf16)(O[i][nt][r] * inv);
        *(bf16x4*)(yq + nt * 16 + quad * 4) = ov;
      }
    }
  }
}

__global__ void fill_kernel(float* out, float v, int n) {
  int i = blockIdx.x * 256 + threadIdx.x;
  if (i < n) out[i] = v;
}

// ---------------------------------------------------------------------------
extern "C" void kernel_launch(void* const* d_in, const int* in_sizes, int n_in,
                              void* d_out, int out_size, void* d_ws, size_t ws_size,
                              hipStream_t stream)
{
  const float* tgt    = (const float*)d_in[0];
  const float* mem    = (const float*)d_in[1];
  const float* sa_Wq  = (const float*)d_in[3];
  const float* sa_Wqb = (const float*)d_in[4];
  const float* sa_Wk  = (const float*)d_in[5];
  const float* sa_Wkb = (const float*)d_in[6];
  const float* sa_Wv  = (const float*)d_in[7];
  const float* sa_Wvb = (const float*)d_in[8];
  const float* sa_A   = (const float*)d_in[9];
  const float* sa_Ab  = (const float*)d_in[10];
  const float* ca_Wq  = (const float*)d_in[11];
  const float* ca_Wqb = (const float*)d_in[12];
  const float* ca_Wk  = (const float*)d_in[13];
  const float* ca_Wkb = (const float*)d_in[14];
  const float* ca_Wv  = (const float*)d_in[15];
  const float* ca_Wvb = (const float*)d_in[16];
  const float* ca_A   = (const float*)d_in[17];
  const float* ca_Ab  = (const float*)d_in[18];
  const float* l1W    = (const float*)d_in[19];
  const float* l1b    = (const float*)d_in[20];
  const float* l2W    = (const float*)d_in[21];
  const float* l2b    = (const float*)d_in[22];
  const float* g1     = (const float*)d_in[23];
  const float* b1     = (const float*)d_in[24];
  const float* g2     = (const float*)d_in[25];
  const float* b2     = (const float*)d_in[26];
  const float* g3     = (const float*)d_in[27];
  const float* b3     = (const float*)d_in[28];

  const size_t MB = 1024 * 1024;
  const size_t NEED = 80 * MB + 4096;
  if (ws_size < NEED) {
    fill_kernel<<<(out_size + 255) / 256, 256, 0, stream>>>((float*)d_out, 3.0f, out_size);
    return;
  }

  char* ws = (char*)d_ws;
  const size_t MD = (size_t)MROWS * EMBED;       // 8M elements
  // phase A
  bf16*  qkv   = (bf16*)ws;                      // [8192][3072] 48 MB
  bf16*  yb    = (bf16*)(ws + 48 * MB);          // 16 MB attention output
  bf16*  wqkvt = (bf16*)(ws + 48 * MB);          // 6 MB weights (dead before fattn writes yb)
  float* qkvbias = (float*)(ws + 54 * MB + 512 * 1024);
  // phase B
  bf16*  kvb   = (bf16*)ws;                      // [8192][2048] 32 MB
  bf16*  qB    = (bf16*)(ws + 32 * MB);          // 16 MB
  bf16*  wkvt  = (bf16*)(ws + 48 * MB);          // 4 MB
  bf16*  wqt   = (bf16*)(ws + 52 * MB);          // 2 MB
  float* kvbias = (float*)(ws + 54 * MB + 512 * 1024);
  // shared
  bf16*  awt   = (bf16*)ws;                      // 2 MB out-proj Wt (qkv/kvb dead)
  bf16*  xb    = (bf16*)(ws + 64 * MB);          // 16 MB LN output stream
  // phase C
  bf16*  hb    = (bf16*)ws;                      // [8192][2048] 32 MB hidden half
  bf16*  l1t   = (bf16*)(ws + 32 * MB);          // 8 MB
  bf16*  l2t   = (bf16*)(ws + 40 * MB);          // 8 MB
  // d_out regions
  float* P   = (float*)d_out;                    // fp32 pre-LN scratch (32 MB)
  bf16*  inb = (bf16*)d_out;                     // converted tgt/mem (16 MB)
  bf16*  vtg = (bf16*)((char*)d_out + 16 * MB);  // V^T for attention (16 MB)

  dim3 blk(256);
  dim3 gQKV(3072 / 128, MROWS / 128);   // (24,64)
  dim3 gKV(2048 / 128, MROWS / 128);    // (16,64)
  dim3 gEE(EMBED / 128, MROWS / 128);   // (8,64)
  dim3 gF1(2048 / 128, MROWS / 128);    // (16,64)
  dim3 gATC(SEQ / 256, BATCH * HEADS);  // (8,64)  causal: paired q-tiles
  dim3 gAT(SEQ / 128, BATCH * HEADS);   // (16,64) cross
  dim3 gVT(SEQ / 64, BATCH * HEADS);    // (32,64)
  dim3 gWee(16, 16);
  const int ncv = (int)(MD / 8 / 256);

  // ---- Phase A: self-attention ----
  cvt_kernel<<<ncv, blk, 0, stream>>>(tgt, inb, (int)MD);
  wt_kernel<<<gWee, blk, 0, stream>>>(sa_Wq, wqkvt, EMBED, EMBED);
  wt_kernel<<<gWee, blk, 0, stream>>>(sa_Wk, wqkvt + 1024 * 1024, EMBED, EMBED);
  wt_kernel<<<gWee, blk, 0, stream>>>(sa_Wv, wqkvt + 2 * 1024 * 1024, EMBED, EMBED);
  cat3_kernel<<<12, blk, 0, stream>>>(qkvbias, sa_Wqb, sa_Wkb, sa_Wvb, EMBED);
  gemm128<<<gQKV, blk, 0, stream>>>(inb, EMBED, wqkvt, EMBED, qkvbias, nullptr, nullptr, qkv, nullptr, 3072, EMBED, 0);
  vtr_kernel<<<gVT, blk, 0, stream>>>(qkv + 2048, 3072, vtg, SEQ);
  fattn_kernel<<<gATC, blk, 0, stream>>>(qkv, 3072, qkv + 1024, 3072, vtg, yb, SEQ, 1);
  wt_kernel<<<gWee, blk, 0, stream>>>(sa_A, awt, EMBED, EMBED);
  gemm128<<<gEE, blk, 0, stream>>>(yb, EMBED, awt, EMBED, sa_Ab, nullptr, tgt, nullptr, P, EMBED, EMBED, 0);
  ln_kernel<<<MROWS, blk, 0, stream>>>(P, g1, b1, xb, nullptr);

  // ---- Phase B: cross-attention ----
  cvt_kernel<<<ncv, blk, 0, stream>>>(mem, inb, (int)MD);
  wt_kernel<<<gWee, blk, 0, stream>>>(ca_Wk, wkvt, EMBED, EMBED);
  wt_kernel<<<gWee, blk, 0, stream>>>(ca_Wv, wkvt + 1024 * 1024, EMBED, EMBED);
  wt_kernel<<<gWee, blk, 0, stream>>>(ca_Wq, wqt, EMBED, EMBED);
  cat3_kernel<<<8, blk, 0, stream>>>(kvbias, ca_Wkb, ca_Wvb, nullptr, EMBED);
  gemm128<<<gKV, blk, 0, stream>>>(inb, EMBED, wkvt, EMBED, kvbias, nullptr, nullptr, kvb, nullptr, 2048, EMBED, 0);
  gemm128<<<gEE, blk, 0, stream>>>(xb, EMBED, wqt, EMBED, ca_Wqb, nullptr, nullptr, qB, nullptr, EMBED, EMBED, 0);
  vtr_kernel<<<gVT, blk, 0, stream>>>(kvb + 1024, 2048, vtg, SEQ);
  fattn_kernel<<<gAT, blk, 0, stream>>>(qB, 1024, kvb, 2048, vtg, yb, SEQ, 0);
  wt_kernel<<<gWee, blk, 0, stream>>>(ca_A, awt, EMBED, EMBED);
  gemm128<<<gEE, blk, 0, stream>>>(yb, EMBED, awt, EMBED, ca_Ab, xb, nullptr, nullptr, P, EMBED, EMBED, 0);
  ln_kernel<<<MROWS, blk, 0, stream>>>(P, g2, b2, xb, nullptr);

  // ---- Phase C: FFN (split-K over DFF halves) ----
  wt_kernel<<<dim3(16, 64), blk, 0, stream>>>(l1W, l1t, EMBED, DFF);
  wt_kernel<<<dim3(64, 16), blk, 0, stream>>>(l2W, l2t, DFF, EMBED);
  gemm128<<<gF1, blk, 0, stream>>>(xb, EMBED, l1t, EMBED, l1b, nullptr, nullptr, hb, nullptr, 2048, EMBED, 1);
  gemm128<<<gEE, blk, 0, stream>>>(hb, 2048, l2t, DFF, l2b, xb, nullptr, nullptr, P, EMBED, 2048, 0);
  gemm128<<<gF1, blk, 0, stream>>>(xb, EMBED, l1t + (size_t)2048 * 1024, EMBED, l1b + 2048, nullptr, nullptr, hb, nullptr, 2048, EMBED, 1);
  gemm128<<<gEE, blk, 0, stream>>>(hb, 2048, l2t + 2048, DFF, nullptr, nullptr, P, nullptr, P, EMBED, 2048, 0);
  ln_kernel<<<MROWS, blk, 0, stream>>>(P, g3, b3, nullptr, (float*)d_out);
}

// Round 12
// 1015.343 us; speedup vs baseline: 1.1381x; 1.0336x over previous
//
#include <hip/hip_runtime.h>

typedef __bf16 bf16;
typedef __bf16 bf16x4 __attribute__((ext_vector_type(4)));
typedef __bf16 bf16x8 __attribute__((ext_vector_type(8)));
typedef float  f32x4  __attribute__((ext_vector_type(4)));

#define EMBED 1024
#define HEADS 16
#define HDIM  64
#define DFF   4096
#define BATCH 4
#define SEQ   2048
#define MROWS 8192   // BATCH*SEQ

// ---------------------------------------------------------------------------
// fp32 -> bf16 elementwise convert (n multiple of 8)
// ---------------------------------------------------------------------------
__global__ __launch_bounds__(256) void cvt_kernel(
    const float* __restrict__ x, bf16* __restrict__ y, int n)
{
  int i = (blockIdx.x * 256 + threadIdx.x) * 8;
  if (i >= n) return;
  float4 a = *(const float4*)(x + i);
  float4 b = *(const float4*)(x + i + 4);
  bf16x8 v;
  v[0] = (bf16)a.x; v[1] = (bf16)a.y; v[2] = (bf16)a.z; v[3] = (bf16)a.w;
  v[4] = (bf16)b.x; v[5] = (bf16)b.y; v[6] = (bf16)b.z; v[7] = (bf16)b.w;
  *(bf16x8*)(y + i) = v;
}

// ---------------------------------------------------------------------------
// Weight transpose-convert: W[K][N] fp32 -> Wt[N][K] bf16. 64x64 tile via LDS.
// ---------------------------------------------------------------------------
__global__ __launch_bounds__(256) void wt_kernel(
    const float* __restrict__ W, bf16* __restrict__ Wt, int K, int N)
{
  __shared__ __align__(16) float Ls[64 * 68];
  const int k0 = blockIdx.x * 64, n0 = blockIdx.y * 64;
  const int ty = threadIdx.x >> 4, tx = threadIdx.x & 15;
  #pragma unroll
  for (int r = 0; r < 4; ++r) {
    const int k = ty + r * 16;
    float4 v = *(const float4*)(W + (size_t)(k0 + k) * N + n0 + tx * 4);
    *(float4*)(Ls + k * 68 + tx * 4) = v;
  }
  __syncthreads();
  #pragma unroll
  for (int it = 0; it < 2; ++it) {
    const int c = it * 256 + threadIdx.x;
    const int n = c >> 3, kc = (c & 7) * 8;
    bf16x8 v;
    #pragma unroll
    for (int j = 0; j < 8; ++j) v[j] = (bf16)Ls[(kc + j) * 68 + n];
    *(bf16x8*)(Wt + (size_t)(n0 + n) * K + k0 + kc) = v;
  }
}

// ---------------------------------------------------------------------------
// bias concat: dst[0:n)=a, [n:2n)=b, [2n:3n)=c (c optional)
// ---------------------------------------------------------------------------
__global__ void cat3_kernel(float* __restrict__ dst, const float* __restrict__ a,
                            const float* __restrict__ b, const float* __restrict__ c, int n)
{
  int i = blockIdx.x * 256 + threadIdx.x;
  if (i < n) dst[i] = a[i];
  else if (i < 2 * n) dst[i] = b[i - n];
  else if (c && i < 3 * n) dst[i] = c[i - 2 * n];
}

// ---------------------------------------------------------------------------
// V transpose for attention: V[(b*Skv+key)*ldv + h*64 + d] ->
// Vt[((b*16+h)*64 + d)*Skv + key].  64key x 64d tile via LDS.
// ---------------------------------------------------------------------------
__global__ __launch_bounds__(256) void vtr_kernel(
    const bf16* __restrict__ V, int ldv, bf16* __restrict__ Vt, int Skv)
{
  __shared__ __align__(16) bf16 Ls[64 * 72];
  const int k0 = blockIdx.x * 64;
  const int bh = blockIdx.y, b = bh >> 4, h = bh & 15;
  const int t = threadIdx.x;
  {
    const int key = t >> 2, dc = (t & 3) * 16;
    const bf16* src = V + (size_t)(b * Skv + k0 + key) * ldv + h * HDIM + dc;
    bf16x8 a0 = *(const bf16x8*)src;
    bf16x8 a1 = *(const bf16x8*)(src + 8);
    *(bf16x8*)(Ls + key * 72 + dc) = a0;
    *(bf16x8*)(Ls + key * 72 + dc + 8) = a1;
  }
  __syncthreads();
  {
    const int d = t >> 2, kc = (t & 3) * 16;
    bf16x8 v0, v1;
    #pragma unroll
    for (int j = 0; j < 8; ++j) v0[j] = Ls[(kc + j) * 72 + d];
    #pragma unroll
    for (int j = 0; j < 8; ++j) v1[j] = Ls[(kc + 8 + j) * 72 + d];
    bf16* dst = Vt + ((size_t)(bh * HDIM + d)) * Skv + k0 + kc;
    *(bf16x8*)dst = v0;
    *(bf16x8*)(dst + 8) = v1;
  }
}

// ---------------------------------------------------------------------------
// async global->LDS, 16B per lane
// ---------------------------------------------------------------------------
__device__ __forceinline__ void gll16(const bf16* g, bf16* l) {
  __builtin_amdgcn_global_load_lds(
      (const __attribute__((address_space(1))) unsigned*)g,
      (__attribute__((address_space(3))) unsigned*)l, 16, 0, 0);
}

// ---------------------------------------------------------------------------
// 128x128-tile GEMM, 3-buffer counted-vmcnt pipeline (T4) + LDS XOR swizzle.
// Round-8 verified form (no min-waves hint — round 10 showed the VGPR cap
// causes spills; LDS 48 KiB bounds 3 blk/CU).
// ---------------------------------------------------------------------------
__global__ __launch_bounds__(256) void gemm128(
    const bf16* __restrict__ A, int lda, const bf16* __restrict__ Bt, int ldb,
    const float* __restrict__ bias, const bf16* __restrict__ res_b,
    const float* __restrict__ res_f, bf16* __restrict__ out_b,
    float* __restrict__ out_f, int N, int K, int relu)
{
  __shared__ __align__(16) bf16 As[3][128 * 32];
  __shared__ __align__(16) bf16 Bs[3][128 * 32];
  const int tid  = threadIdx.x;
  const int lane = tid & 63, wave = tid >> 6;
  const int quad = lane >> 4, l16 = lane & 15;
  const int wm = wave & 1, wn = wave >> 1;

  const int gx   = gridDim.x;
  const int nwg  = gx * gridDim.y;
  const int flat = blockIdx.y * gx + blockIdx.x;
  const int wg   = (flat & 7) * (nwg >> 3) + (flat >> 3);   // bijective: nwg%8==0
  const int m0 = (wg / gx) * 128, n0 = (wg % gx) * 128;

  const int c0row = tid >> 2;
  const int c0kc  = (((tid & 3) ^ ((tid >> 2) & 3) ^ ((tid >> 4) & 3))) * 8;
  const int c1row = 64 + c0row;

  const int co = ((quad ^ ((l16 & 3) ^ ((l16 >> 2) & 3)))) * 8;

  const bf16* a0 = A  + (size_t)(m0 + c0row) * lda + c0kc;
  const bf16* b0 = Bt + (size_t)(n0 + c0row) * ldb + c0kc;
  const bf16* a1 = A  + (size_t)(m0 + c1row) * lda + c0kc;
  const bf16* b1 = Bt + (size_t)(n0 + c1row) * ldb + c0kc;

  f32x4 acc[4][4];
  #pragma unroll
  for (int i = 0; i < 4; ++i)
    #pragma unroll
    for (int j = 0; j < 4; ++j) acc[i][j] = f32x4{0, 0, 0, 0};

  auto stage = [&](int k0, int buf) {
    gll16(a0 + k0, As[buf] + wave * 512);
    gll16(b0 + k0, Bs[buf] + wave * 512);
    gll16(a1 + k0, As[buf] + 2048 + wave * 512);
    gll16(b1 + k0, Bs[buf] + 2048 + wave * 512);
  };

  const int nk = K >> 5;
  stage(0, 0);
  if (nk > 1) stage(32, 1);

  int cur = 0;
  for (int t = 0; t < nk; ++t) {
    if (t + 1 < nk) asm volatile("s_waitcnt vmcnt(4)" ::: "memory");
    else            asm volatile("s_waitcnt vmcnt(0)" ::: "memory");
    __builtin_amdgcn_s_barrier();
    __builtin_amdgcn_sched_barrier(0);

    bf16x8 af[4], bfr[4];
    #pragma unroll
    for (int i = 0; i < 4; ++i)
      af[i] = *(const bf16x8*)(As[cur] + (wm * 64 + i * 16 + l16) * 32 + co);
    #pragma unroll
    for (int j = 0; j < 4; ++j)
      bfr[j] = *(const bf16x8*)(Bs[cur] + (wn * 64 + j * 16 + l16) * 32 + co);
    #pragma unroll
    for (int i = 0; i < 4; ++i)
      #pragma unroll
      for (int j = 0; j < 4; ++j)
        acc[i][j] = __builtin_amdgcn_mfma_f32_16x16x32_bf16(af[i], bfr[j], acc[i][j], 0, 0, 0);

    if (t + 2 < nk) {
      int nb = cur + 2; if (nb >= 3) nb -= 3;
      stage((t + 2) << 5, nb);
    }
    cur = (cur + 1 == 3) ? 0 : cur + 1;
  }

  #pragma unroll
  for (int j = 0; j < 4; ++j) {
    const int col = n0 + wn * 64 + j * 16 + l16;
    const float bv = bias ? bias[col] : 0.f;
    #pragma unroll
    for (int i = 0; i < 4; ++i) {
      #pragma unroll
      for (int r = 0; r < 4; ++r) {
        const int row = m0 + wm * 64 + i * 16 + quad * 4 + r;
        const size_t idx = (size_t)row * N + col;
        float v = acc[i][j][r] + bv;
        if (res_b) v += (float)res_b[idx];
        if (res_f) v += res_f[idx];
        if (relu)  v = fmaxf(v, 0.f);
        if (out_b) out_b[idx] = (bf16)v;
        if (out_f) out_f[idx] = v;
      }
    }
  }
}

// ---------------------------------------------------------------------------
// LayerNorm over last dim (1024): fp32 in, fp32 params, bf16 and/or fp32 out.
// ---------------------------------------------------------------------------
__global__ __launch_bounds__(256) void ln_kernel(
    const float* __restrict__ x, const float* __restrict__ g, const float* __restrict__ b,
    bf16* __restrict__ out_b, float* __restrict__ out_f)
{
  __shared__ float red[8];
  const int tid = threadIdx.x, lane = tid & 63, wave = tid >> 6;
  const float* xr = x + (size_t)blockIdx.x * EMBED;
  float4 v = *(const float4*)(xr + tid * 4);
  float vv[4] = {v.x, v.y, v.z, v.w};
  float s  = vv[0] + vv[1] + vv[2] + vv[3];
  float s2 = vv[0]*vv[0] + vv[1]*vv[1] + vv[2]*vv[2] + vv[3]*vv[3];
  #pragma unroll
  for (int off = 32; off >= 1; off >>= 1) {
    s  += __shfl_xor(s, off);
    s2 += __shfl_xor(s2, off);
  }
  if (lane == 0) { red[wave] = s; red[4 + wave] = s2; }
  __syncthreads();
  s  = red[0] + red[1] + red[2] + red[3];
  s2 = red[4] + red[5] + red[6] + red[7];
  const float mu  = s * (1.f / EMBED);
  const float var = s2 * (1.f / EMBED) - mu * mu;
  const float rs  = rsqrtf(fmaxf(var, 0.f) + 1e-5f);
  #pragma unroll
  for (int i = 0; i < 4; ++i) {
    const int col = tid * 4 + i;
    const float o = (vv[i] - mu) * rs * g[col] + b[col];
    const size_t idx = (size_t)blockIdx.x * EMBED + col;
    if (out_b) out_b[idx] = (bf16)o;
    if (out_f) out_f[idx] = o;
  }
}

// ---------------------------------------------------------------------------
// MFMA flash attention.  Swapped QK^T (mfma(K,Q)) => lane-local softmax.
// Transposed PV (mfma(V,P)) => O^T (col=l16->q, reg=quad*4+r->d): identical
// fragment reads, but rescale and 1/l are lane-local (no shuffles) and the
// epilogue is 8 b64 stores/lane.  exp via __expf (fast intrinsic — the
// standard exp2f takes hipcc's precise libm path and cost +10% VALU in
// rounds 5 & 11).  K/V staged via global_load_lds (linear dest + swizzled
// source/read), double-buffered, prefetch-before-compute, one barrier per
// K-tile.  Causal grid pairs q-tiles bx and 15-bx (load balance).
// ---------------------------------------------------------------------------
__global__ __launch_bounds__(256) void fattn_kernel(
    const bf16* __restrict__ Q, int ldq, const bf16* __restrict__ K, int ldk,
    const bf16* __restrict__ Vt, bf16* __restrict__ Y, int Skv, int causal)
{
  constexpr int PLD = 72;                       // P-buffer stride (conflict-free)
  __shared__ __align__(16) bf16 Ks[2][64 * 64]; // [key][d], swizzled
  __shared__ __align__(16) bf16 Vs[2][64 * 64]; // [d][key], swizzled
  __shared__ __align__(16) bf16 Ps[4 * 32 * PLD];

  const int tid  = threadIdx.x;
  const int lane = tid & 63, wave = tid >> 6;
  const int quad = lane >> 4, l16 = lane & 15;
  const int bh = blockIdx.y, b = bh >> 4, h = bh & 15;

  const bf16* Kb = K + (size_t)b * Skv * ldk + h * HDIM;
  const bf16* Vb = Vt + (size_t)(bh * HDIM) * Skv;

  const int sr = lane >> 3;
  const int se = ((lane & 7) ^ sr) << 3;        // swizzled source elem offset

  const int sw  = l16 & 7;
  const int co0 = (quad ^ sw) << 3;
  const int co1 = ((4 + quad) ^ sw) << 3;

  auto stage = [&](int kt, int buf) {
    const int k0 = kt * 64;
    const int r0 = wave * 16;
    gll16(Kb + (size_t)(k0 + r0 + sr) * ldk + se,     &Ks[buf][(r0)     * 64]);
    gll16(Kb + (size_t)(k0 + r0 + 8 + sr) * ldk + se, &Ks[buf][(r0 + 8) * 64]);
    gll16(Vb + (size_t)(r0 + sr) * Skv + k0 + se,     &Vs[buf][(r0)     * 64]);
    gll16(Vb + (size_t)(r0 + 8 + sr) * Skv + k0 + se, &Vs[buf][(r0 + 8) * 64]);
  };

  bf16* Pw = Ps + wave * 32 * PLD;
  const int npass = causal ? 2 : 1;

  for (int pass = 0; pass < npass; ++pass) {
    const int qt = causal ? (pass == 0 ? (int)blockIdx.x
                                       : (SEQ / 128 - 1 - (int)blockIdx.x))
                          : (int)blockIdx.x;
    const int q0  = qt * 128;
    const int wq0 = q0 + wave * 32;

    bf16x8 qf[2][2];
    #pragma unroll
    for (int i = 0; i < 2; ++i) {
      const bf16* qp = Q + (size_t)(b * SEQ + wq0 + i * 16 + l16) * ldq + h * HDIM;
      qf[i][0] = *(const bf16x8*)(qp + quad * 8);
      qf[i][1] = *(const bf16x8*)(qp + 32 + quad * 8);
    }

    f32x4 O[2][4];                              // O^T: [i][d-tile nt], col=q
    float m_run[2], l_run[2];
    #pragma unroll
    for (int i = 0; i < 2; ++i)
      #pragma unroll
      for (int nt = 0; nt < 4; ++nt) O[i][nt] = f32x4{0, 0, 0, 0};
    #pragma unroll
    for (int i = 0; i < 2; ++i) { m_run[i] = -1e30f; l_run[i] = 0.f; }

    const int nkt = causal ? (q0 / 64 + 2) : (Skv / 64);

    stage(0, 0);
    __syncthreads();

    for (int kt = 0; kt < nkt; ++kt) {
      const int cur = kt & 1;
      const int k0 = kt * 64;
      if (kt + 1 < nkt) stage(kt + 1, cur ^ 1);

      const bf16* Kc = Ks[cur];
      const bf16* Vc = Vs[cur];

      // ---- S^T = K Q^T  (col=l16 -> q, row=quad*4+r -> key), raw (unscaled)
      f32x4 s[2][4];
      __builtin_amdgcn_s_setprio(1);
      #pragma unroll
      for (int nt = 0; nt < 4; ++nt) {
        const int row = nt * 16 + l16;
        bf16x8 kf0 = *(const bf16x8*)(Kc + row * 64 + co0);
        bf16x8 kf1 = *(const bf16x8*)(Kc + row * 64 + co1);
        #pragma unroll
        for (int i = 0; i < 2; ++i) {
          f32x4 t = f32x4{0, 0, 0, 0};
          t = __builtin_amdgcn_mfma_f32_16x16x32_bf16(kf0, qf[i][0], t, 0, 0, 0);
          t = __builtin_amdgcn_mfma_f32_16x16x32_bf16(kf1, qf[i][1], t, 0, 0, 0);
          s[i][nt] = t;
        }
      }
      __builtin_amdgcn_s_setprio(0);

      if (causal && (k0 + 63 > wq0)) {          // mask only on diagonal tiles
        #pragma unroll
        for (int i = 0; i < 2; ++i) {
          const int q = wq0 + i * 16 + l16;
          #pragma unroll
          for (int nt = 0; nt < 4; ++nt) {
            #pragma unroll
            for (int r = 0; r < 4; ++r) {
              const int key = k0 + nt * 16 + quad * 4 + r;
              if (key > q) s[i][nt][r] = -1e30f;
            }
          }
        }
      }

      // ---- online softmax: raw-domain max, scale folded into __expf via fma
      #pragma unroll
      for (int i = 0; i < 2; ++i) {
        float pm = s[i][0][0];
        #pragma unroll
        for (int nt = 0; nt < 4; ++nt)
          #pragma unroll
          for (int r = 0; r < 4; ++r) pm = fmaxf(pm, s[i][nt][r]);
        pm = fmaxf(pm, __shfl_xor(pm, 16));
        pm = fmaxf(pm, __shfl_xor(pm, 32));
        const float m_new = fmaxf(m_run[i], pm);
        const float al = __expf((m_run[i] - m_new) * 0.125f);
        m_run[i] = m_new;
        const float mc = m_new * 0.125f;
        float ls = 0.f;
        #pragma unroll
        for (int nt = 0; nt < 4; ++nt) {
          #pragma unroll
          for (int r = 0; r < 4; ++r) {
            const float e = __expf(fmaf(s[i][nt][r], 0.125f, -mc));
            s[i][nt][r] = e;
            ls += e;
          }
        }
        ls += __shfl_xor(ls, 16);
        ls += __shfl_xor(ls, 32);
        l_run[i] = l_run[i] * al + ls;
        // P store: row q=i*16+l16, keys nt*16+quad*4..+3 contiguous -> b64
        #pragma unroll
        for (int nt = 0; nt < 4; ++nt) {
          bf16x4 pk;
          pk[0] = (bf16)s[i][nt][0]; pk[1] = (bf16)s[i][nt][1];
          pk[2] = (bf16)s[i][nt][2]; pk[3] = (bf16)s[i][nt][3];
          *(bf16x4*)(Pw + (i * 16 + l16) * PLD + nt * 16 + quad * 4) = pk;
        }
        // O^T rescale: this lane's O[i][*] all have q = i*16+l16 -> al is
        // lane-local (quad-uniform softmax state).  No shuffles.
        #pragma unroll
        for (int nt = 0; nt < 4; ++nt)
          #pragma unroll
          for (int r = 0; r < 4; ++r) O[i][nt][r] *= al;
      }

      // ---- O^T += V^T P^T : mfma(vf, pf) — identical frag reads, swapped
      bf16x8 pf[2][2];
      #pragma unroll
      for (int i = 0; i < 2; ++i) {
        pf[i][0] = *(const bf16x8*)(Pw + (i * 16 + l16) * PLD + quad * 8);
        pf[i][1] = *(const bf16x8*)(Pw + (i * 16 + l16) * PLD + 32 + quad * 8);
      }
      __builtin_amdgcn_s_setprio(1);
      #pragma unroll
      for (int nt = 0; nt < 4; ++nt) {
        const int row = nt * 16 + l16;
        bf16x8 vf0 = *(const bf16x8*)(Vc + row * 64 + co0);
        bf16x8 vf1 = *(const bf16x8*)(Vc + row * 64 + co1);
        #pragma unroll
        for (int i = 0; i < 2; ++i) {
          O[i][nt] = __builtin_amdgcn_mfma_f32_16x16x32_bf16(vf0, pf[i][0], O[i][nt], 0, 0, 0);
          O[i][nt] = __builtin_amdgcn_mfma_f32_16x16x32_bf16(vf1, pf[i][1], O[i][nt], 0, 0, 0);
        }
      }
      __builtin_amdgcn_s_setprio(0);
      __syncthreads();
    }

    // ---- epilogue: O^T[d=nt*16+quad*4+r][q=i*16+l16]; inv lane-local;
    //      per (i,nt) a contiguous bf16x4 at d-offset nt*16+quad*4.
    #pragma unroll
    for (int i = 0; i < 2; ++i) {
      const float inv = 1.f / l_run[i];
      bf16* yq = Y + ((size_t)(b * SEQ + wq0 + i * 16 + l16)) * EMBED + h * HDIM;
      #pragma unroll
      for (int nt = 0; nt < 4; ++nt) {
        bf16x4 ov;
        #pragma unroll
        for (int r = 0; r < 4; ++r) ov[r] = (bf16)(O[i][nt][r] * inv);
        *(bf16x4*)(yq + nt * 16 + quad * 4) = ov;
      }
    }
  }
}

__global__ void fill_kernel(float* out, float v, int n) {
  int i = blockIdx.x * 256 + threadIdx.x;
  if (i < n) out[i] = v;
}

// ---------------------------------------------------------------------------
extern "C" void kernel_launch(void* const* d_in, const int* in_sizes, int n_in,
                              void* d_out, int out_size, void* d_ws, size_t ws_size,
                              hipStream_t stream)
{
  const float* tgt    = (const float*)d_in[0];
  const float* mem    = (const float*)d_in[1];
  const float* sa_Wq  = (const float*)d_in[3];
  const float* sa_Wqb = (const float*)d_in[4];
  const float* sa_Wk  = (const float*)d_in[5];
  const float* sa_Wkb = (const float*)d_in[6];
  const float* sa_Wv  = (const float*)d_in[7];
  const float* sa_Wvb = (const float*)d_in[8];
  const float* sa_A   = (const float*)d_in[9];
  const float* sa_Ab  = (const float*)d_in[10];
  const float* ca_Wq  = (const float*)d_in[11];
  const float* ca_Wqb = (const float*)d_in[12];
  const float* ca_Wk  = (const float*)d_in[13];
  const float* ca_Wkb = (const float*)d_in[14];
  const float* ca_Wv  = (const float*)d_in[15];
  const float* ca_Wvb = (const float*)d_in[16];
  const float* ca_A   = (const float*)d_in[17];
  const float* ca_Ab  = (const float*)d_in[18];
  const float* l1W    = (const float*)d_in[19];
  const float* l1b    = (const float*)d_in[20];
  const float* l2W    = (const float*)d_in[21];
  const float* l2b    = (const float*)d_in[22];
  const float* g1     = (const float*)d_in[23];
  const float* b1     = (const float*)d_in[24];
  const float* g2     = (const float*)d_in[25];
  const float* b2     = (const float*)d_in[26];
  const float* g3     = (const float*)d_in[27];
  const float* b3     = (const float*)d_in[28];

  const size_t MB = 1024 * 1024;
  const size_t NEED = 80 * MB + 4096;
  if (ws_size < NEED) {
    fill_kernel<<<(out_size + 255) / 256, 256, 0, stream>>>((float*)d_out, 3.0f, out_size);
    return;
  }

  char* ws = (char*)d_ws;
  const size_t MD = (size_t)MROWS * EMBED;       // 8M elements
  // phase A
  bf16*  qkv   = (bf16*)ws;                      // [8192][3072] 48 MB
  bf16*  yb    = (bf16*)(ws + 48 * MB);          // 16 MB attention output
  bf16*  wqkvt = (bf16*)(ws + 48 * MB);          // 6 MB weights (dead before fattn writes yb)
  float* qkvbias = (float*)(ws + 54 * MB + 512 * 1024);
  // phase B
  bf16*  kvb   = (bf16*)ws;                      // [8192][2048] 32 MB
  bf16*  qB    = (bf16*)(ws + 32 * MB);          // 16 MB
  bf16*  wkvt  = (bf16*)(ws + 48 * MB);          // 4 MB
  bf16*  wqt   = (bf16*)(ws + 52 * MB);          // 2 MB
  float* kvbias = (float*)(ws + 54 * MB + 512 * 1024);
  // shared
  bf16*  awt   = (bf16*)ws;                      // 2 MB out-proj Wt (qkv/kvb dead)
  bf16*  xb    = (bf16*)(ws + 64 * MB);          // 16 MB LN output stream
  // phase C
  bf16*  hb    = (bf16*)ws;                      // [8192][2048] 32 MB hidden half
  bf16*  l1t   = (bf16*)(ws + 32 * MB);          // 8 MB
  bf16*  l2t   = (bf16*)(ws + 40 * MB);          // 8 MB
  // d_out regions
  float* P   = (float*)d_out;                    // fp32 pre-LN scratch (32 MB)
  bf16*  inb = (bf16*)d_out;                     // converted tgt/mem (16 MB)
  bf16*  vtg = (bf16*)((char*)d_out + 16 * MB);  // V^T for attention (16 MB)

  dim3 blk(256);
  dim3 gQKV(3072 / 128, MROWS / 128);   // (24,64)
  dim3 gKV(2048 / 128, MROWS / 128);    // (16,64)
  dim3 gEE(EMBED / 128, MROWS / 128);   // (8,64)
  dim3 gF1(2048 / 128, MROWS / 128);    // (16,64)
  dim3 gATC(SEQ / 256, BATCH * HEADS);  // (8,64)  causal: paired q-tiles
  dim3 gAT(SEQ / 128, BATCH * HEADS);   // (16,64) cross
  dim3 gVT(SEQ / 64, BATCH * HEADS);    // (32,64)
  dim3 gWee(16, 16);
  const int ncv = (int)(MD / 8 / 256);

  // ---- Phase A: self-attention ----
  cvt_kernel<<<ncv, blk, 0, stream>>>(tgt, inb, (int)MD);
  wt_kernel<<<gWee, blk, 0, stream>>>(sa_Wq, wqkvt, EMBED, EMBED);
  wt_kernel<<<gWee, blk, 0, stream>>>(sa_Wk, wqkvt + 1024 * 1024, EMBED, EMBED);
  wt_kernel<<<gWee, blk, 0, stream>>>(sa_Wv, wqkvt + 2 * 1024 * 1024, EMBED, EMBED);
  cat3_kernel<<<12, blk, 0, stream>>>(qkvbias, sa_Wqb, sa_Wkb, sa_Wvb, EMBED);
  gemm128<<<gQKV, blk, 0, stream>>>(inb, EMBED, wqkvt, EMBED, qkvbias, nullptr, nullptr, qkv, nullptr, 3072, EMBED, 0);
  vtr_kernel<<<gVT, blk, 0, stream>>>(qkv + 2048, 3072, vtg, SEQ);
  fattn_kernel<<<gATC, blk, 0, stream>>>(qkv, 3072, qkv + 1024, 3072, vtg, yb, SEQ, 1);
  wt_kernel<<<gWee, blk, 0, stream>>>(sa_A, awt, EMBED, EMBED);
  gemm128<<<gEE, blk, 0, stream>>>(yb, EMBED, awt, EMBED, sa_Ab, nullptr, tgt, nullptr, P, EMBED, EMBED, 0);
  ln_kernel<<<MROWS, blk, 0, stream>>>(P, g1, b1, xb, nullptr);

  // ---- Phase B: cross-attention ----
  cvt_kernel<<<ncv, blk, 0, stream>>>(mem, inb, (int)MD);
  wt_kernel<<<gWee, blk, 0, stream>>>(ca_Wk, wkvt, EMBED, EMBED);
  wt_kernel<<<gWee, blk, 0, stream>>>(ca_Wv, wkvt + 1024 * 1024, EMBED, EMBED);
  wt_kernel<<<gWee, blk, 0, stream>>>(ca_Wq, wqt, EMBED, EMBED);
  cat3_kernel<<<8, blk, 0, stream>>>(kvbias, ca_Wkb, ca_Wvb, nullptr, EMBED);
  gemm128<<<gKV, blk, 0, stream>>>(inb, EMBED, wkvt, EMBED, kvbias, nullptr, nullptr, kvb, nullptr, 2048, EMBED, 0);
  gemm128<<<gEE, blk, 0, stream>>>(xb, EMBED, wqt, EMBED, ca_Wqb, nullptr, nullptr, qB, nullptr, EMBED, EMBED, 0);
  vtr_kernel<<<gVT, blk, 0, stream>>>(kvb + 1024, 2048, vtg, SEQ);
  fattn_kernel<<<gAT, blk, 0, stream>>>(qB, 1024, kvb, 2048, vtg, yb, SEQ, 0);
  wt_kernel<<<gWee, blk, 0, stream>>>(ca_A, awt, EMBED, EMBED);
  gemm128<<<gEE, blk, 0, stream>>>(yb, EMBED, awt, EMBED, ca_Ab, xb, nullptr, nullptr, P, EMBED, EMBED, 0);
  ln_kernel<<<MROWS, blk, 0, stream>>>(P, g2, b2, xb, nullptr);

  // ---- Phase C: FFN (split-K over DFF halves) ----
  wt_kernel<<<dim3(16, 64), blk, 0, stream>>>(l1W, l1t, EMBED, DFF);
  wt_kernel<<<dim3(64, 16), blk, 0, stream>>>(l2W, l2t, DFF, EMBED);
  gemm128<<<gF1, blk, 0, stream>>>(xb, EMBED, l1t, EMBED, l1b, nullptr, nullptr, hb, nullptr, 2048, EMBED, 1);
  gemm128<<<gEE, blk, 0, stream>>>(hb, 2048, l2t, DFF, l2b, xb, nullptr, nullptr, P, EMBED, 2048, 0);
  gemm128<<<gF1, blk, 0, stream>>>(xb, EMBED, l1t + (size_t)2048 * 1024, EMBED, l1b + 2048, nullptr, nullptr, hb, nullptr, 2048, EMBED, 1);
  gemm128<<<gEE, blk, 0, stream>>>(hb, 2048, l2t + 2048, DFF, nullptr, nullptr, P, nullptr, P, EMBED, 2048, 0);
  ln_kernel<<<MROWS, blk, 0, stream>>>(P, g3, b3, nullptr, (float*)d_out);
}

// Round 13
// 1014.834 us; speedup vs baseline: 1.1387x; 1.0005x over previous
//
#include <hip/hip_runtime.h>

typedef __bf16 bf16;
typedef __bf16 bf16x4 __attribute__((ext_vector_type(4)));
typedef __bf16 bf16x8 __attribute__((ext_vector_type(8)));
typedef float  f32x4  __attribute__((ext_vector_type(4)));

#define EMBED 1024
#define HEADS 16
#define HDIM  64
#define DFF   4096
#define BATCH 4
#define SEQ   2048
#define MROWS 8192   // BATCH*SEQ

// ---------------------------------------------------------------------------
// fp32 -> bf16 elementwise convert (n multiple of 8)
// ---------------------------------------------------------------------------
__global__ __launch_bounds__(256) void cvt_kernel(
    const float* __restrict__ x, bf16* __restrict__ y, int n)
{
  int i = (blockIdx.x * 256 + threadIdx.x) * 8;
  if (i >= n) return;
  float4 a = *(const float4*)(x + i);
  float4 b = *(const float4*)(x + i + 4);
  bf16x8 v;
  v[0] = (bf16)a.x; v[1] = (bf16)a.y; v[2] = (bf16)a.z; v[3] = (bf16)a.w;
  v[4] = (bf16)b.x; v[5] = (bf16)b.y; v[6] = (bf16)b.z; v[7] = (bf16)b.w;
  *(bf16x8*)(y + i) = v;
}

// ---------------------------------------------------------------------------
// Weight transpose-convert: W[K][N] fp32 -> Wt[N][K] bf16. 64x64 tile via LDS.
// ---------------------------------------------------------------------------
__global__ __launch_bounds__(256) void wt_kernel(
    const float* __restrict__ W, bf16* __restrict__ Wt, int K, int N)
{
  __shared__ __align__(16) float Ls[64 * 68];
  const int k0 = blockIdx.x * 64, n0 = blockIdx.y * 64;
  const int ty = threadIdx.x >> 4, tx = threadIdx.x & 15;
  #pragma unroll
  for (int r = 0; r < 4; ++r) {
    const int k = ty + r * 16;
    float4 v = *(const float4*)(W + (size_t)(k0 + k) * N + n0 + tx * 4);
    *(float4*)(Ls + k * 68 + tx * 4) = v;
  }
  __syncthreads();
  #pragma unroll
  for (int it = 0; it < 2; ++it) {
    const int c = it * 256 + threadIdx.x;
    const int n = c >> 3, kc = (c & 7) * 8;
    bf16x8 v;
    #pragma unroll
    for (int j = 0; j < 8; ++j) v[j] = (bf16)Ls[(kc + j) * 68 + n];
    *(bf16x8*)(Wt + (size_t)(n0 + n) * K + k0 + kc) = v;
  }
}

// ---------------------------------------------------------------------------
// bias concat: dst[0:n)=a, [n:2n)=b, [2n:3n)=c (c optional)
// ---------------------------------------------------------------------------
__global__ void cat3_kernel(float* __restrict__ dst, const float* __restrict__ a,
                            const float* __restrict__ b, const float* __restrict__ c, int n)
{
  int i = blockIdx.x * 256 + threadIdx.x;
  if (i < n) dst[i] = a[i];
  else if (i < 2 * n) dst[i] = b[i - n];
  else if (c && i < 3 * n) dst[i] = c[i - 2 * n];
}

// ---------------------------------------------------------------------------
// V transpose for attention: V[(b*Skv+key)*ldv + h*64 + d] ->
// Vt[((b*16+h)*64 + d)*Skv + key].  64key x 64d tile via LDS.
// ---------------------------------------------------------------------------
__global__ __launch_bounds__(256) void vtr_kernel(
    const bf16* __restrict__ V, int ldv, bf16* __restrict__ Vt, int Skv)
{
  __shared__ __align__(16) bf16 Ls[64 * 72];
  const int k0 = blockIdx.x * 64;
  const int bh = blockIdx.y, b = bh >> 4, h = bh & 15;
  const int t = threadIdx.x;
  {
    const int key = t >> 2, dc = (t & 3) * 16;
    const bf16* src = V + (size_t)(b * Skv + k0 + key) * ldv + h * HDIM + dc;
    bf16x8 a0 = *(const bf16x8*)src;
    bf16x8 a1 = *(const bf16x8*)(src + 8);
    *(bf16x8*)(Ls + key * 72 + dc) = a0;
    *(bf16x8*)(Ls + key * 72 + dc + 8) = a1;
  }
  __syncthreads();
  {
    const int d = t >> 2, kc = (t & 3) * 16;
    bf16x8 v0, v1;
    #pragma unroll
    for (int j = 0; j < 8; ++j) v0[j] = Ls[(kc + j) * 72 + d];
    #pragma unroll
    for (int j = 0; j < 8; ++j) v1[j] = Ls[(kc + 8 + j) * 72 + d];
    bf16* dst = Vt + ((size_t)(bh * HDIM + d)) * Skv + k0 + kc;
    *(bf16x8*)dst = v0;
    *(bf16x8*)(dst + 8) = v1;
  }
}

// ---------------------------------------------------------------------------
// async global->LDS, 16B per lane
// ---------------------------------------------------------------------------
__device__ __forceinline__ void gll16(const bf16* g, bf16* l) {
  __builtin_amdgcn_global_load_lds(
      (const __attribute__((address_space(1))) unsigned*)g,
      (__attribute__((address_space(3))) unsigned*)l, 16, 0, 0);
}

// ---------------------------------------------------------------------------
// 128x128-tile GEMM, 3-buffer counted-vmcnt pipeline (T4) + LDS XOR swizzle.
// Round-8 verified form (no min-waves hint — round 10 showed the VGPR cap
// causes spills; LDS 48 KiB bounds 3 blk/CU).
// ---------------------------------------------------------------------------
__global__ __launch_bounds__(256) void gemm128(
    const bf16* __restrict__ A, int lda, const bf16* __restrict__ Bt, int ldb,
    const float* __restrict__ bias, const bf16* __restrict__ res_b,
    const float* __restrict__ res_f, bf16* __restrict__ out_b,
    float* __restrict__ out_f, int N, int K, int relu)
{
  __shared__ __align__(16) bf16 As[3][128 * 32];
  __shared__ __align__(16) bf16 Bs[3][128 * 32];
  const int tid  = threadIdx.x;
  const int lane = tid & 63, wave = tid >> 6;
  const int quad = lane >> 4, l16 = lane & 15;
  const int wm = wave & 1, wn = wave >> 1;

  const int gx   = gridDim.x;
  const int nwg  = gx * gridDim.y;
  const int flat = blockIdx.y * gx + blockIdx.x;
  const int wg   = (flat & 7) * (nwg >> 3) + (flat >> 3);   // bijective: nwg%8==0
  const int m0 = (wg / gx) * 128, n0 = (wg % gx) * 128;

  const int c0row = tid >> 2;
  const int c0kc  = (((tid & 3) ^ ((tid >> 2) & 3) ^ ((tid >> 4) & 3))) * 8;
  const int c1row = 64 + c0row;

  const int co = ((quad ^ ((l16 & 3) ^ ((l16 >> 2) & 3)))) * 8;

  const bf16* a0 = A  + (size_t)(m0 + c0row) * lda + c0kc;
  const bf16* b0 = Bt + (size_t)(n0 + c0row) * ldb + c0kc;
  const bf16* a1 = A  + (size_t)(m0 + c1row) * lda + c0kc;
  const bf16* b1 = Bt + (size_t)(n0 + c1row) * ldb + c0kc;

  f32x4 acc[4][4];
  #pragma unroll
  for (int i = 0; i < 4; ++i)
    #pragma unroll
    for (int j = 0; j < 4; ++j) acc[i][j] = f32x4{0, 0, 0, 0};

  auto stage = [&](int k0, int buf) {
    gll16(a0 + k0, As[buf] + wave * 512);
    gll16(b0 + k0, Bs[buf] + wave * 512);
    gll16(a1 + k0, As[buf] + 2048 + wave * 512);
    gll16(b1 + k0, Bs[buf] + 2048 + wave * 512);
  };

  const int nk = K >> 5;
  stage(0, 0);
  if (nk > 1) stage(32, 1);

  int cur = 0;
  for (int t = 0; t < nk; ++t) {
    if (t + 1 < nk) asm volatile("s_waitcnt vmcnt(4)" ::: "memory");
    else            asm volatile("s_waitcnt vmcnt(0)" ::: "memory");
    __builtin_amdgcn_s_barrier();
    __builtin_amdgcn_sched_barrier(0);

    bf16x8 af[4], bfr[4];
    #pragma unroll
    for (int i = 0; i < 4; ++i)
      af[i] = *(const bf16x8*)(As[cur] + (wm * 64 + i * 16 + l16) * 32 + co);
    #pragma unroll
    for (int j = 0; j < 4; ++j)
      bfr[j] = *(const bf16x8*)(Bs[cur] + (wn * 64 + j * 16 + l16) * 32 + co);
    #pragma unroll
    for (int i = 0; i < 4; ++i)
      #pragma unroll
      for (int j = 0; j < 4; ++j)
        acc[i][j] = __builtin_amdgcn_mfma_f32_16x16x32_bf16(af[i], bfr[j], acc[i][j], 0, 0, 0);

    if (t + 2 < nk) {
      int nb = cur + 2; if (nb >= 3) nb -= 3;
      stage((t + 2) << 5, nb);
    }
    cur = (cur + 1 == 3) ? 0 : cur + 1;
  }

  #pragma unroll
  for (int j = 0; j < 4; ++j) {
    const int col = n0 + wn * 64 + j * 16 + l16;
    const float bv = bias ? bias[col] : 0.f;
    #pragma unroll
    for (int i = 0; i < 4; ++i) {
      #pragma unroll
      for (int r = 0; r < 4; ++r) {
        const int row = m0 + wm * 64 + i * 16 + quad * 4 + r;
        const size_t idx = (size_t)row * N + col;
        float v = acc[i][j][r] + bv;
        if (res_b) v += (float)res_b[idx];
        if (res_f) v += res_f[idx];
        if (relu)  v = fmaxf(v, 0.f);
        if (out_b) out_b[idx] = (bf16)v;
        if (out_f) out_f[idx] = v;
      }
    }
  }
}

// ---------------------------------------------------------------------------
// LayerNorm over last dim (1024): fp32 in, fp32 params, bf16 and/or fp32 out.
// ---------------------------------------------------------------------------
__global__ __launch_bounds__(256) void ln_kernel(
    const float* __restrict__ x, const float* __restrict__ g, const float* __restrict__ b,
    bf16* __restrict__ out_b, float* __restrict__ out_f)
{
  __shared__ float red[8];
  const int tid = threadIdx.x, lane = tid & 63, wave = tid >> 6;
  const float* xr = x + (size_t)blockIdx.x * EMBED;
  float4 v = *(const float4*)(xr + tid * 4);
  float vv[4] = {v.x, v.y, v.z, v.w};
  float s  = vv[0] + vv[1] + vv[2] + vv[3];
  float s2 = vv[0]*vv[0] + vv[1]*vv[1] + vv[2]*vv[2] + vv[3]*vv[3];
  #pragma unroll
  for (int off = 32; off >= 1; off >>= 1) {
    s  += __shfl_xor(s, off);
    s2 += __shfl_xor(s2, off);
  }
  if (lane == 0) { red[wave] = s; red[4 + wave] = s2; }
  __syncthreads();
  s  = red[0] + red[1] + red[2] + red[3];
  s2 = red[4] + red[5] + red[6] + red[7];
  const float mu  = s * (1.f / EMBED);
  const float var = s2 * (1.f / EMBED) - mu * mu;
  const float rs  = rsqrtf(fmaxf(var, 0.f) + 1e-5f);
  #pragma unroll
  for (int i = 0; i < 4; ++i) {
    const int col = tid * 4 + i;
    const float o = (vv[i] - mu) * rs * g[col] + b[col];
    const size_t idx = (size_t)blockIdx.x * EMBED + col;
    if (out_b) out_b[idx] = (bf16)o;
    if (out_f) out_f[idx] = o;
  }
}

// ---------------------------------------------------------------------------
// MFMA flash attention.  Swapped QK^T (mfma(K,Q)) => lane-local softmax;
// transposed PV (mfma(V,P)) => O^T with lane-local rescale/1/l + coalesced
// epilogue (round-12 verified).  LDS DIET (this round): Ps shrunk 18->8 KB
// via (a) i-split reuse — P-store/pf-read for i=0 complete before i=1's
// stores (per-wave LDS ops are in-order), 16 rows instead of 32; (b) stride
// 72->64 with the SAME XOR-16B swizzle as K/V (write block
// (nt*2+(quad>>1))^(l16&7), read co0/co1 — 2 lanes/16B block = free).
// Total LDS 40 KB -> 4 blocks/CU for the 1024-block cross-attn dispatch
// (was 3): one more resident block of TLP to hide the softmax VALU chain.
// exp via __expf (fast path; std exp2f cost +10% VALU, rounds 5/11).
// K/V staged via global_load_lds, double-buffered, one barrier per K-tile.
// Causal grid pairs q-tiles bx and 15-bx (load balance).
// ---------------------------------------------------------------------------
__global__ __launch_bounds__(256) void fattn_kernel(
    const bf16* __restrict__ Q, int ldq, const bf16* __restrict__ K, int ldk,
    const bf16* __restrict__ Vt, bf16* __restrict__ Y, int Skv, int causal)
{
  __shared__ __align__(16) bf16 Ks[2][64 * 64]; // [key][d], swizzled
  __shared__ __align__(16) bf16 Vs[2][64 * 64]; // [d][key], swizzled
  __shared__ __align__(16) bf16 Ps[4 * 16 * 64]; // per-wave 16 rows, swizzled

  const int tid  = threadIdx.x;
  const int lane = tid & 63, wave = tid >> 6;
  const int quad = lane >> 4, l16 = lane & 15;
  const int bh = blockIdx.y, b = bh >> 4, h = bh & 15;

  const bf16* Kb = K + (size_t)b * Skv * ldk + h * HDIM;
  const bf16* Vb = Vt + (size_t)(bh * HDIM) * Skv;

  const int sr = lane >> 3;
  const int se = ((lane & 7) ^ sr) << 3;        // swizzled source elem offset

  const int sw  = l16 & 7;
  const int co0 = (quad ^ sw) << 3;
  const int co1 = ((4 + quad) ^ sw) << 3;

  auto stage = [&](int kt, int buf) {
    const int k0 = kt * 64;
    const int r0 = wave * 16;
    gll16(Kb + (size_t)(k0 + r0 + sr) * ldk + se,     &Ks[buf][(r0)     * 64]);
    gll16(Kb + (size_t)(k0 + r0 + 8 + sr) * ldk + se, &Ks[buf][(r0 + 8) * 64]);
    gll16(Vb + (size_t)(r0 + sr) * Skv + k0 + se,     &Vs[buf][(r0)     * 64]);
    gll16(Vb + (size_t)(r0 + 8 + sr) * Skv + k0 + se, &Vs[buf][(r0 + 8) * 64]);
  };

  bf16* Pw = Ps + wave * 16 * 64;
  // P-store swizzled sub-block offsets (per nt): logical block nt*2+(quad>>1)
  const int psub = (quad & 1) * 4;
  const int npass = causal ? 2 : 1;

  for (int pass = 0; pass < npass; ++pass) {
    const int qt = causal ? (pass == 0 ? (int)blockIdx.x
                                       : (SEQ / 128 - 1 - (int)blockIdx.x))
                          : (int)blockIdx.x;
    const int q0  = qt * 128;
    const int wq0 = q0 + wave * 32;

    bf16x8 qf[2][2];
    #pragma unroll
    for (int i = 0; i < 2; ++i) {
      const bf16* qp = Q + (size_t)(b * SEQ + wq0 + i * 16 + l16) * ldq + h * HDIM;
      qf[i][0] = *(const bf16x8*)(qp + quad * 8);
      qf[i][1] = *(const bf16x8*)(qp + 32 + quad * 8);
    }

    f32x4 O[2][4];                              // O^T: [i][d-tile nt], col=q
    float m_run[2], l_run[2];
    #pragma unroll
    for (int i = 0; i < 2; ++i)
      #pragma unroll
      for (int nt = 0; nt < 4; ++nt) O[i][nt] = f32x4{0, 0, 0, 0};
    #pragma unroll
    for (int i = 0; i < 2; ++i) { m_run[i] = -1e30f; l_run[i] = 0.f; }

    const int nkt = causal ? (q0 / 64 + 2) : (Skv / 64);

    stage(0, 0);
    __syncthreads();

    for (int kt = 0; kt < nkt; ++kt) {
      const int cur = kt & 1;
      const int k0 = kt * 64;
      if (kt + 1 < nkt) stage(kt + 1, cur ^ 1);

      const bf16* Kc = Ks[cur];
      const bf16* Vc = Vs[cur];

      // ---- S^T = K Q^T  (col=l16 -> q, row=quad*4+r -> key), raw (unscaled)
      f32x4 s[2][4];
      __builtin_amdgcn_s_setprio(1);
      #pragma unroll
      for (int nt = 0; nt < 4; ++nt) {
        const int row = nt * 16 + l16;
        bf16x8 kf0 = *(const bf16x8*)(Kc + row * 64 + co0);
        bf16x8 kf1 = *(const bf16x8*)(Kc + row * 64 + co1);
        #pragma unroll
        for (int i = 0; i < 2; ++i) {
          f32x4 t = f32x4{0, 0, 0, 0};
          t = __builtin_amdgcn_mfma_f32_16x16x32_bf16(kf0, qf[i][0], t, 0, 0, 0);
          t = __builtin_amdgcn_mfma_f32_16x16x32_bf16(kf1, qf[i][1], t, 0, 0, 0);
          s[i][nt] = t;
        }
      }
      __builtin_amdgcn_s_setprio(0);

      if (causal && (k0 + 63 > wq0)) {          // mask only on diagonal tiles
        #pragma unroll
        for (int i = 0; i < 2; ++i) {
          const int q = wq0 + i * 16 + l16;
          #pragma unroll
          for (int nt = 0; nt < 4; ++nt) {
            #pragma unroll
            for (int r = 0; r < 4; ++r) {
              const int key = k0 + nt * 16 + quad * 4 + r;
              if (key > q) s[i][nt][r] = -1e30f;
            }
          }
        }
      }

      // ---- online softmax + P store/read, i-split over the shared 16-row Ps
      bf16x8 pf[2][2];
      #pragma unroll
      for (int i = 0; i < 2; ++i) {
        float pm = s[i][0][0];
        #pragma unroll
        for (int nt = 0; nt < 4; ++nt)
          #pragma unroll
          for (int r = 0; r < 4; ++r) pm = fmaxf(pm, s[i][nt][r]);
        pm = fmaxf(pm, __shfl_xor(pm, 16));
        pm = fmaxf(pm, __shfl_xor(pm, 32));
        const float m_new = fmaxf(m_run[i], pm);
        const float al = __expf((m_run[i] - m_new) * 0.125f);
        m_run[i] = m_new;
        const float mc = m_new * 0.125f;
        float ls = 0.f;
        #pragma unroll
        for (int nt = 0; nt < 4; ++nt) {
          #pragma unroll
          for (int r = 0; r < 4; ++r) {
            const float e = __expf(fmaf(s[i][nt][r], 0.125f, -mc));
            s[i][nt][r] = e;
            ls += e;
          }
        }
        ls += __shfl_xor(ls, 16);
        ls += __shfl_xor(ls, 32);
        l_run[i] = l_run[i] * al + ls;
        // P store: row l16, logical elems nt*16+quad*4 -> swizzled block
        #pragma unroll
        for (int nt = 0; nt < 4; ++nt) {
          bf16x4 pk;
          pk[0] = (bf16)s[i][nt][0]; pk[1] = (bf16)s[i][nt][1];
          pk[2] = (bf16)s[i][nt][2]; pk[3] = (bf16)s[i][nt][3];
          const int pblk = ((nt * 2 + (quad >> 1)) ^ sw) << 3;
          *(bf16x4*)(Pw + l16 * 64 + pblk + psub) = pk;
        }
        // pf read BEFORE i=1 overwrites (per-wave LDS ops are in-order)
        pf[i][0] = *(const bf16x8*)(Pw + l16 * 64 + co0);
        pf[i][1] = *(const bf16x8*)(Pw + l16 * 64 + co1);
        // O^T rescale: lane-local al (quad-uniform state), no shuffles
        #pragma unroll
        for (int nt = 0; nt < 4; ++nt)
          #pragma unroll
          for (int r = 0; r < 4; ++r) O[i][nt][r] *= al;
      }

      // ---- O^T += V^T P^T : mfma(vf, pf), V read once per nt
      __builtin_amdgcn_s_setprio(1);
      #pragma unroll
      for (int nt = 0; nt < 4; ++nt) {
        const int row = nt * 16 + l16;
        bf16x8 vf0 = *(const bf16x8*)(Vc + row * 64 + co0);
        bf16x8 vf1 = *(const bf16x8*)(Vc + row * 64 + co1);
        #pragma unroll
        for (int i = 0; i < 2; ++i) {
          O[i][nt] = __builtin_amdgcn_mfma_f32_16x16x32_bf16(vf0, pf[i][0], O[i][nt], 0, 0, 0);
          O[i][nt] = __builtin_amdgcn_mfma_f32_16x16x32_bf16(vf1, pf[i][1], O[i][nt], 0, 0, 0);
        }
      }
      __builtin_amdgcn_s_setprio(0);
      __syncthreads();
    }

    // ---- epilogue: O^T[d=nt*16+quad*4+r][q=i*16+l16]; inv lane-local;
    //      per (i,nt) a contiguous bf16x4 at d-offset nt*16+quad*4.
    #pragma unroll
    for (int i = 0; i < 2; ++i) {
      const float inv = 1.f / l_run[i];
      bf16* yq = Y + ((size_t)(b * SEQ + wq0 + i * 16 + l16)) * EMBED + h * HDIM;
      #pragma unroll
      for (int nt = 0; nt < 4; ++nt) {
        bf16x4 ov;
        #pragma unroll
        for (int r = 0; r < 4; ++r) ov[r] = (bf16)(O[i][nt][r] * inv);
        *(bf16x4*)(yq + nt * 16 + quad * 4) = ov;
      }
    }
  }
}

__global__ void fill_kernel(float* out, float v, int n) {
  int i = blockIdx.x * 256 + threadIdx.x;
  if (i < n) out[i] = v;
}

// ---------------------------------------------------------------------------
extern "C" void kernel_launch(void* const* d_in, const int* in_sizes, int n_in,
                              void* d_out, int out_size, void* d_ws, size_t ws_size,
                              hipStream_t stream)
{
  const float* tgt    = (const float*)d_in[0];
  const float* mem    = (const float*)d_in[1];
  const float* sa_Wq  = (const float*)d_in[3];
  const float* sa_Wqb = (const float*)d_in[4];
  const float* sa_Wk  = (const float*)d_in[5];
  const float* sa_Wkb = (const float*)d_in[6];
  const float* sa_Wv  = (const float*)d_in[7];
  const float* sa_Wvb = (const float*)d_in[8];
  const float* sa_A   = (const float*)d_in[9];
  const float* sa_Ab  = (const float*)d_in[10];
  const float* ca_Wq  = (const float*)d_in[11];
  const float* ca_Wqb = (const float*)d_in[12];
  const float* ca_Wk  = (const float*)d_in[13];
  const float* ca_Wkb = (const float*)d_in[14];
  const float* ca_Wv  = (const float*)d_in[15];
  const float* ca_Wvb = (const float*)d_in[16];
  const float* ca_A   = (const float*)d_in[17];
  const float* ca_Ab  = (const float*)d_in[18];
  const float* l1W    = (const float*)d_in[19];
  const float* l1b    = (const float*)d_in[20];
  const float* l2W    = (const float*)d_in[21];
  const float* l2b    = (const float*)d_in[22];
  const float* g1     = (const float*)d_in[23];
  const float* b1     = (const float*)d_in[24];
  const float* g2     = (const float*)d_in[25];
  const float* b2     = (const float*)d_in[26];
  const float* g3     = (const float*)d_in[27];
  const float* b3     = (const float*)d_in[28];

  const size_t MB = 1024 * 1024;
  const size_t NEED = 80 * MB + 4096;
  if (ws_size < NEED) {
    fill_kernel<<<(out_size + 255) / 256, 256, 0, stream>>>((float*)d_out, 3.0f, out_size);
    return;
  }

  char* ws = (char*)d_ws;
  const size_t MD = (size_t)MROWS * EMBED;       // 8M elements
  // phase A
  bf16*  qkv   = (bf16*)ws;                      // [8192][3072] 48 MB
  bf16*  yb    = (bf16*)(ws + 48 * MB);          // 16 MB attention output
  bf16*  wqkvt = (bf16*)(ws + 48 * MB);          // 6 MB weights (dead before fattn writes yb)
  float* qkvbias = (float*)(ws + 54 * MB + 512 * 1024);
  // phase B
  bf16*  kvb   = (bf16*)ws;                      // [8192][2048] 32 MB
  bf16*  qB    = (bf16*)(ws + 32 * MB);          // 16 MB
  bf16*  wkvt  = (bf16*)(ws + 48 * MB);          // 4 MB
  bf16*  wqt   = (bf16*)(ws + 52 * MB);          // 2 MB
  float* kvbias = (float*)(ws + 54 * MB + 512 * 1024);
  // shared
  bf16*  awt   = (bf16*)ws;                      // 2 MB out-proj Wt (qkv/kvb dead)
  bf16*  xb    = (bf16*)(ws + 64 * MB);          // 16 MB LN output stream
  // phase C
  bf16*  hb    = (bf16*)ws;                      // [8192][2048] 32 MB hidden half
  bf16*  l1t   = (bf16*)(ws + 32 * MB);          // 8 MB
  bf16*  l2t   = (bf16*)(ws + 40 * MB);          // 8 MB
  // d_out regions
  float* P   = (float*)d_out;                    // fp32 pre-LN scratch (32 MB)
  bf16*  inb = (bf16*)d_out;                     // converted tgt/mem (16 MB)
  bf16*  vtg = (bf16*)((char*)d_out + 16 * MB);  // V^T for attention (16 MB)

  dim3 blk(256);
  dim3 gQKV(3072 / 128, MROWS / 128);   // (24,64)
  dim3 gKV(2048 / 128, MROWS / 128);    // (16,64)
  dim3 gEE(EMBED / 128, MROWS / 128);   // (8,64)
  dim3 gF1(2048 / 128, MROWS / 128);    // (16,64)
  dim3 gATC(SEQ / 256, BATCH * HEADS);  // (8,64)  causal: paired q-tiles
  dim3 gAT(SEQ / 128, BATCH * HEADS);   // (16,64) cross
  dim3 gVT(SEQ / 64, BATCH * HEADS);    // (32,64)
  dim3 gWee(16, 16);
  const int ncv = (int)(MD / 8 / 256);

  // ---- Phase A: self-attention ----
  cvt_kernel<<<ncv, blk, 0, stream>>>(tgt, inb, (int)MD);
  wt_kernel<<<gWee, blk, 0, stream>>>(sa_Wq, wqkvt, EMBED, EMBED);
  wt_kernel<<<gWee, blk, 0, stream>>>(sa_Wk, wqkvt + 1024 * 1024, EMBED, EMBED);
  wt_kernel<<<gWee, blk, 0, stream>>>(sa_Wv, wqkvt + 2 * 1024 * 1024, EMBED, EMBED);
  cat3_kernel<<<12, blk, 0, stream>>>(qkvbias, sa_Wqb, sa_Wkb, sa_Wvb, EMBED);
  gemm128<<<gQKV, blk, 0, stream>>>(inb, EMBED, wqkvt, EMBED, qkvbias, nullptr, nullptr, qkv, nullptr, 3072, EMBED, 0);
  vtr_kernel<<<gVT, blk, 0, stream>>>(qkv + 2048, 3072, vtg, SEQ);
  fattn_kernel<<<gATC, blk, 0, stream>>>(qkv, 3072, qkv + 1024, 3072, vtg, yb, SEQ, 1);
  wt_kernel<<<gWee, blk, 0, stream>>>(sa_A, awt, EMBED, EMBED);
  gemm128<<<gEE, blk, 0, stream>>>(yb, EMBED, awt, EMBED, sa_Ab, nullptr, tgt, nullptr, P, EMBED, EMBED, 0);
  ln_kernel<<<MROWS, blk, 0, stream>>>(P, g1, b1, xb, nullptr);

  // ---- Phase B: cross-attention ----
  cvt_kernel<<<ncv, blk, 0, stream>>>(mem, inb, (int)MD);
  wt_kernel<<<gWee, blk, 0, stream>>>(ca_Wk, wkvt, EMBED, EMBED);
  wt_kernel<<<gWee, blk, 0, stream>>>(ca_Wv, wkvt + 1024 * 1024, EMBED, EMBED);
  wt_kernel<<<gWee, blk, 0, stream>>>(ca_Wq, wqt, EMBED, EMBED);
  cat3_kernel<<<8, blk, 0, stream>>>(kvbias, ca_Wkb, ca_Wvb, nullptr, EMBED);
  gemm128<<<gKV, blk, 0, stream>>>(inb, EMBED, wkvt, EMBED, kvbias, nullptr, nullptr, kvb, nullptr, 2048, EMBED, 0);
  gemm128<<<gEE, blk, 0, stream>>>(xb, EMBED, wqt, EMBED, ca_Wqb, nullptr, nullptr, qB, nullptr, EMBED, EMBED, 0);
  vtr_kernel<<<gVT, blk, 0, stream>>>(kvb + 1024, 2048, vtg, SEQ);
  fattn_kernel<<<gAT, blk, 0, stream>>>(qB, 1024, kvb, 2048, vtg, yb, SEQ, 0);
  wt_kernel<<<gWee, blk, 0, stream>>>(ca_A, awt, EMBED, EMBED);
  gemm128<<<gEE, blk, 0, stream>>>(yb, EMBED, awt, EMBED, ca_Ab, xb, nullptr, nullptr, P, EMBED, EMBED, 0);
  ln_kernel<<<MROWS, blk, 0, stream>>>(P, g2, b2, xb, nullptr);

  // ---- Phase C: FFN (split-K over DFF halves) ----
  wt_kernel<<<dim3(16, 64), blk, 0, stream>>>(l1W, l1t, EMBED, DFF);
  wt_kernel<<<dim3(64, 16), blk, 0, stream>>>(l2W, l2t, DFF, EMBED);
  gemm128<<<gF1, blk, 0, stream>>>(xb, EMBED, l1t, EMBED, l1b, nullptr, nullptr, hb, nullptr, 2048, EMBED, 1);
  gemm128<<<gEE, blk, 0, stream>>>(hb, 2048, l2t, DFF, l2b, xb, nullptr, nullptr, P, EMBED, 2048, 0);
  gemm128<<<gF1, blk, 0, stream>>>(xb, EMBED, l1t + (size_t)2048 * 1024, EMBED, l1b + 2048, nullptr, nullptr, hb, nullptr, 2048, EMBED, 1);
  gemm128<<<gEE, blk, 0, stream>>>(hb, 2048, l2t + 2048, DFF, nullptr, nullptr, P, nullptr, P, EMBED, 2048, 0);
  ln_kernel<<<MROWS, blk, 0, stream>>>(P, g3, b3, nullptr, (float*)d_out);
}